// Round 10
// baseline (1022.074 us; speedup 1.0000x reference)
//
#include <hip/hip_runtime.h>
#include <hip/hip_bf16.h>
#include <cstdint>
#include <cstddef>

// B=2048, D=256, H=256, N=64, F=513, 4H=1024

typedef short s16x8 __attribute__((ext_vector_type(8)));
typedef float f32x4 __attribute__((ext_vector_type(4)));
typedef int   i32x4 __attribute__((ext_vector_type(4)));

static __device__ __forceinline__ unsigned short f2b(float f){
  union{float f; unsigned int u;} v; v.f = f;
  unsigned int r = v.u + 0x7fffu + ((v.u >> 16) & 1u);   // RNE
  return (unsigned short)(r >> 16);
}
static __device__ __forceinline__ float b2f(unsigned short h){
  union{unsigned int u; float f;} v; v.u = ((unsigned int)h) << 16; return v.f;
}
static __device__ __forceinline__ float fsig(float x){ return 1.0f / (1.0f + __expf(-x)); }
static __device__ __forceinline__ float ftanh(float x){ return 2.0f / (1.0f + __expf(-2.0f * x)) - 1.0f; }
static __device__ __forceinline__ float wred(float p){
  p += __shfl_down(p, 32); p += __shfl_down(p, 16); p += __shfl_down(p, 8);
  p += __shfl_down(p, 4);  p += __shfl_down(p, 2);  p += __shfl_down(p, 1);
  return p;
}
// async global->LDS, 16 B per lane; lds base must be wave-uniform
static __device__ __forceinline__ void gload16(const void* g, void* lds){
  __builtin_amdgcn_global_load_lds(
      (const __attribute__((address_space(1))) unsigned int*)g,
      (__attribute__((address_space(3))) unsigned int*)lds, 16, 0, 0);
}
// 8 fp32 -> 8 bf16 via HW pack-convert (RNE)
static __device__ __forceinline__ s16x8 cvt8(float4 lo, float4 hi){
  union { unsigned int u[4]; s16x8 v; } r;
  asm("v_cvt_pk_bf16_f32 %0, %1, %2" : "=v"(r.u[0]) : "v"(lo.x), "v"(lo.y));
  asm("v_cvt_pk_bf16_f32 %0, %1, %2" : "=v"(r.u[1]) : "v"(lo.z), "v"(lo.w));
  asm("v_cvt_pk_bf16_f32 %0, %1, %2" : "=v"(r.u[2]) : "v"(hi.x), "v"(hi.y));
  asm("v_cvt_pk_bf16_f32 %0, %1, %2" : "=v"(r.u[3]) : "v"(hi.z), "v"(hi.w));
  return r.v;
}

#define WSCALE (0.30f / 127.0f)      // W_hh i8 scale

// ---------------------------------------------------------------------------
// K0: weight prep. wfB: W_ih bf16 B-fragments, kt-major (frag = kt*64 + ct).
// wfrag8: W_hh int8 B-fragments for k_lstm. bias = b_ih+b_hh; wlast = W_ih[:,512].
// ---------------------------------------------------------------------------
__global__ __launch_bounds__(256) void k_prep(
    const float* __restrict__ wih, const float* __restrict__ whh,
    const float* __restrict__ bih, const float* __restrict__ bhh,
    unsigned short* __restrict__ wfB, signed char* __restrict__ wfrag8,
    float* __restrict__ bias, float* __restrict__ wlast){
  int id = blockIdx.x * 256 + threadIdx.x;          // grid covers 524288
  { // wfB: 1024 frags * 512 entries, kt-major
    int frag = id >> 9;
    int l = (id >> 3) & 63;
    int j = id & 7;
    int kt = frag >> 6, ct = frag & 63;
    int col = ct * 16 + (l & 15);
    int k   = kt * 32 + (l >> 4) * 8 + j;
    wfB[id] = f2b(wih[col * 513 + k]);
  }
  if (id < 262144){ // wfrag8: 512 frags * 512 entries, int8
    int frag = id >> 9;
    int lane = (id >> 3) & 63;
    int j    = id & 7;
    int w  = frag >> 6;
    int kt = (frag >> 3) & 7;
    int nt = frag & 7;
    int g  = nt >> 1, hh = nt & 1;
    int colg = g * 256 + w * 32 + hh * 16 + (lane & 15);
    int k    = kt * 32 + (lane >> 4) * 8 + j;
    int q = __float2int_rn(whh[colg * 256 + k] * (1.0f / WSCALE));
    q = q > 127 ? 127 : (q < -127 ? -127 : q);
    wfrag8[frag * 512 + lane * 8 + j] = (signed char)q;
  }
  if (id < 1024){
    bias[id]  = bih[id] + bhh[id];
    wlast[id] = wih[id * 513 + 512];
  }
}

// ---------------------------------------------------------------------------
// K1: routing (fast path = first empty slot via ballot; sims fallback kept).
// ---------------------------------------------------------------------------
__global__ __launch_bounds__(256) void k_route(
    const float* __restrict__ x, const float* __restrict__ slots,
    const float* __restrict__ delta, const int* __restrict__ filled,
    const float* __restrict__ Wq, const float* __restrict__ Wk,
    const float* __restrict__ Wv, const float* __restrict__ bv,
    int* __restrict__ idx_ws, float* __restrict__ v_ws,
    float* __restrict__ delta_out, float* __restrict__ filled_out){
  int b = blockIdx.x, tid = threadIdx.x, l = tid & 63, w = tid >> 6;
  __shared__ float xs[256], qs[256], qks[256], sims[64];
  __shared__ int sidx;
  xs[tid] = x[b * 256 + tid];
  if (tid < 64){
    unsigned long long em = __ballot(filled[b * 64 + tid] == 0);
    if (tid == 0) sidx = em ? (int)__builtin_ctzll(em) : -1;
  }
  __syncthreads();
  for (int t = 0; t < 64; ++t){
    int h = w * 64 + t;
    float pv = 0.f;
    #pragma unroll
    for (int j2 = 0; j2 < 4; ++j2)
      pv += Wv[h * 256 + l + 64 * j2] * xs[l + 64 * j2];
    pv = wred(pv);
    if (l == 0) v_ws[b * 256 + h] = pv + bv[h];
  }
  if (sidx < 0){           // rare fallback: content-based argmax
    for (int t = 0; t < 64; ++t){
      int h = w * 64 + t;
      float p = 0.f;
      #pragma unroll
      for (int j2 = 0; j2 < 4; ++j2)
        p += Wq[h * 256 + l + 64 * j2] * xs[l + 64 * j2];
      p = wred(p);
      if (l == 0) qs[h] = p;
    }
    __syncthreads();
    {
      int d = tid; float p = 0.f;
      for (int h = 0; h < 256; ++h) p += qs[h] * Wk[h * 256 + d];
      qks[d] = p;
    }
    __syncthreads();
    for (int t = 0; t < 16; ++t){
      int n = w * 16 + t;
      float p = 0.f;
      #pragma unroll
      for (int j2 = 0; j2 < 4; ++j2)
        p += slots[(size_t)(b * 64 + n) * 256 + l + 64 * j2] * qks[l + 64 * j2];
      p = wred(p);
      if (l == 0) sims[n] = p;
    }
    __syncthreads();
    if (tid == 0){
      int ic = 0; float best = sims[0];
      for (int n = 1; n < 64; ++n) if (sims[n] > best){ best = sims[n]; ic = n; }
      sidx = ic;
    }
  }
  __syncthreads();
  int id = sidx;
  if (tid == 0) idx_ws[b] = id;
  if (tid < 64){
    int n = tid; bool sel = (n == id);
    delta_out[b * 64 + n]  = sel ? 0.0f : (delta[b * 64 + n] + 1.0f);
    filled_out[b * 64 + n] = (sel || filled[b * 64 + n] != 0) ? 1.0f : 0.0f;
  }
}

// ---------------------------------------------------------------------------
// K2: standalone scatter/copy. slots_out/cum_out = updated mem state (fp32).
// ---------------------------------------------------------------------------
__global__ __launch_bounds__(256) void k_scatter(
    const float* __restrict__ x, const float* __restrict__ slots,
    const float* __restrict__ cum, const int* __restrict__ idx_ws,
    const float* __restrict__ v_ws,
    float* __restrict__ slots_out, float* __restrict__ cum_out){
  int row = blockIdx.x * 4 + (threadIdx.x >> 6);   // global (b,n) row
  int l = threadIdx.x & 63;
  int b = row >> 6, n = row & 63;
  size_t e = (size_t)row * 256 + l * 4;
  float4 s  = *(const float4*)(slots + e);
  float4 cf = *(const float4*)(cum + e);
  float4 xv = *(const float4*)(x + (size_t)b * 256 + l * 4);
  if (n == idx_ws[b]){
    s  = *(const float4*)(v_ws + (size_t)b * 256 + l * 4);
    cf = xv;
  } else {
    cf.x += xv.x; cf.y += xv.y; cf.z += xv.z; cf.w += xv.w;
  }
  *(float4*)(slots_out + e) = s;
  *(float4*)(cum_out + e)   = cf;
}

// ---------------------------------------------------------------------------
// K3 v10: PURE GEMM, bf16 A in LDS. Z0 = [slots_out|cum_out]@W_ih^T + eps.
// A reg-staged (4 float4 loads/lane/kt, T14 split: load early -> MFMA -> cvt
// + ds_write late) into a [kq 0..3][128 rows]x16B bf16 tile (wave w = kq w;
// consecutive-row 16B writes/reads -> conflict-free, single b128 per frag).
// B via gload_lds dbuf from kt-major wfB. One barrier per K-step.
// LDS: A dbuf @0/8192; B dbuf @16384/24576 (32 KB total).
// Grid 8192 XCD-chunked: 8 n-blocks of an m-panel share A via one XCD's L2.
// z0 step-major: z0[(n*2048 + b)*1024 + gc] (bf16).
// ---------------------------------------------------------------------------
__global__ __launch_bounds__(256) void k_gemm(
    const float* __restrict__ Asl, const float* __restrict__ Acu,
    const float* __restrict__ dlt,
    const unsigned short* __restrict__ wfB,
    const float* __restrict__ wlast, const float* __restrict__ bias,
    unsigned short* __restrict__ z0){
  __shared__ unsigned char L[32768];
  int tid = threadIdx.x, l = tid & 63, w = tid >> 6;
  int bid = blockIdx.x;
  int gw = (bid & 7) * 1024 + (bid >> 3);        // XCD-chunked bijection
  int n_idx = gw & 7, m_idx = gw >> 3;
  int m0 = m_idx * 128, n0 = n_idx * 128, bA = m0 >> 6;
  int wm = w & 1, wn = w >> 1, cl = l & 15, lhi = l >> 4;

  auto loadA = [&](int kt, float4* fs){          // lane: rows l and 64+l, kq=w
    const float* srcb = (kt < 8) ? Asl : Acu;
    int kof = (kt & 7) * 32 + w * 8;
    const float* p0 = srcb + (size_t)(m0 + l) * 256 + kof;
    const float* p1 = srcb + (size_t)(m0 + 64 + l) * 256 + kof;
    fs[0] = ((const float4*)p0)[0]; fs[1] = ((const float4*)p0)[1];
    fs[2] = ((const float4*)p1)[0]; fs[3] = ((const float4*)p1)[1];
  };
  auto writeA = [&](const float4* fs, int abase){
    *(s16x8*)(L + abase + w * 2048 + l * 16)        = cvt8(fs[0], fs[1]);
    *(s16x8*)(L + abase + w * 2048 + 1024 + l * 16) = cvt8(fs[2], fs[3]);
  };
  auto stageB = [&](int kt, int bbase){
    const unsigned short* s = wfB + ((size_t)(kt * 64 + n_idx * 8 + w * 2)) * 512 + l * 8;
    gload16(s, L + bbase + w * 2048);
    gload16(s + 512, L + bbase + w * 2048 + 1024);
  };

  f32x4 acc[4][4];
  #pragma unroll
  for (int mi = 0; mi < 4; ++mi)
    #pragma unroll
    for (int ni = 0; ni < 4; ++ni){ f32x4 zr = {0.f,0.f,0.f,0.f}; acc[mi][ni] = zr; }

  {
    float4 fs[4];
    loadA(0, fs);
    stageB(0, 16384);
    writeA(fs, 0);
  }
  __syncthreads();

  for (int kt = 0; kt < 16; ++kt){
    int cur = kt & 1, nxt = cur ^ 1;
    float4 fs[4];
    if (kt < 15){
      loadA(kt + 1, fs);                 // global loads in flight under MFMA
      stageB(kt + 1, 16384 + nxt * 8192);
    }
    int ab = cur * 8192, bb = 16384 + cur * 8192;
    s16x8 a[4], bf[4];
    #pragma unroll
    for (int mi = 0; mi < 4; ++mi)
      a[mi] = *(const s16x8*)(L + ab + lhi * 2048 + (wm * 64 + mi * 16 + cl) * 16);
    #pragma unroll
    for (int ni = 0; ni < 4; ++ni)
      bf[ni] = *(const s16x8*)(L + bb + (wn * 4 + ni) * 1024 + l * 16);
    #pragma unroll
    for (int ni = 0; ni < 4; ++ni)
      #pragma unroll
      for (int mi = 0; mi < 4; ++mi)
        acc[mi][ni] = __builtin_amdgcn_mfma_f32_16x16x32_bf16(a[mi], bf[ni], acc[mi][ni], 0, 0, 0);
    if (kt < 15) writeA(fs, nxt * 8192);  // cvt waits vmcnt here (post-MFMA)
    __syncthreads();
  }

  // epilogue: acc -> L (z-stage, 128 rows x 256 B) -> coalesced z0 stores
  float dv[4][4];
  #pragma unroll
  for (int mi = 0; mi < 4; ++mi)
    #pragma unroll
    for (int reg = 0; reg < 4; ++reg)
      dv[mi][reg] = dlt[(bA + wm) * 64 + mi * 16 + lhi * 4 + reg];
  #pragma unroll
  for (int mi = 0; mi < 4; ++mi)
    #pragma unroll
    for (int reg = 0; reg < 4; ++reg){
      int row = wm * 64 + mi * 16 + lhi * 4 + reg;
      #pragma unroll
      for (int ni = 0; ni < 4; ++ni){
        int col = wn * 64 + ni * 16 + cl;
        int gc = n0 + col;
        float val = acc[mi][ni][reg] + dv[mi][reg] * wlast[gc] + bias[gc];
        *(unsigned short*)(L + row * 256 + ((col * 2) ^ ((row & 7) << 4))) = f2b(val);
      }
    }
  __syncthreads();
  #pragma unroll
  for (int rr = 0; rr < 8; ++rr){
    int row = w * 32 + rr * 4 + lhi;
    int bq = bA + (row >> 6), nq = row & 63;
    uint4 v = *(const uint4*)(L + row * 256 + ((cl * 16) ^ ((row & 7) << 4)));
    *(uint4*)(z0 + ((size_t)nq * 2048 + bq) * 1024 + n0 + cl * 8) = v;
  }
}

// ---------------------------------------------------------------------------
// K4 v6: recurrent LSTM, int8 register-resident W_hh, 256 blocks x 8 rows.
// ---------------------------------------------------------------------------
__global__ __launch_bounds__(512) void k_lstm(
    const unsigned short* __restrict__ z0,
    const signed char* __restrict__ wfrag8,
    float* __restrict__ hm){
  extern __shared__ unsigned char smem[];
  unsigned char* zbuf = smem;                 // 2 x 16 KB
  unsigned char* hbf  = smem + 32768;         // 16 x 256 int8 = 4 KB, swizzled
  int tid = threadIdx.x, l = tid & 63, w = tid >> 6;
  int cl = l & 15, lhi = l >> 4;
  int b0 = blockIdx.x * 8;

  for (int i = tid; i < 1024; i += 512) ((unsigned int*)hbf)[i] = 0u;

  // resident weights: 64 frags x 8 B (128 VGPRs)
  long long wpin[64];
  #pragma unroll
  for (int f = 0; f < 64; ++f)
    wpin[f] = *(const long long*)(wfrag8 + ((size_t)w * 64 + f) * 512 + l * 8);

  // prologue: z slice n=0 -> buf0 (16B-granule row-XOR swizzle)
  {
    const uint4* src = (const uint4*)(z0 + (size_t)b0 * 1024);
    int rr = tid >> 6, off = (tid & 63) * 32;
    unsigned char* base = zbuf + rr * 2048;
    *(uint4*)(base + ((off)      ^ ((rr & 7) << 4))) = src[tid * 2];
    *(uint4*)(base + ((off + 16) ^ ((rr & 7) << 4))) = src[tid * 2 + 1];
  }
  float cst[8];
  #pragma unroll
  for (int i = 0; i < 8; ++i) cst[i] = 0.f;
  const float s_comb = WSCALE / 127.0f;       // acc_i32 -> z_hh f32
  __syncthreads();

  for (int n = 0; n < 64; ++n){
    uint4 zp0, zp1;
    if (n < 63){
      const uint4* src = (const uint4*)(z0 + ((size_t)(n + 1) * 2048 + b0) * 1024);
      zp0 = src[tid * 2]; zp1 = src[tid * 2 + 1];
    }
    i32x4 acc[8];
    #pragma unroll
    for (int nt = 0; nt < 8; ++nt){ i32x4 zr = {0, 0, 0, 0}; acc[nt] = zr; }
    #pragma unroll
    for (int kt = 0; kt < 8; ++kt){
      int byteo = cl * 256 + ((kt * 32 + lhi * 8) ^ ((cl & 7) << 3));
      long long a = *(const long long*)(hbf + byteo);
      #pragma unroll
      for (int nt = 0; nt < 8; ++nt)
        acc[nt] = __builtin_amdgcn_mfma_i32_16x16x32_i8(a, wpin[kt * 8 + nt], acc[nt], 0, 0, 0);
    }
    if (n < 63){
      int rr = tid >> 6, off = (tid & 63) * 32;
      unsigned char* base = zbuf + ((n + 1) & 1) * 16384 + rr * 2048;
      *(uint4*)(base + ((off)      ^ ((rr & 7) << 4))) = zp0;
      *(uint4*)(base + ((off + 16) ^ ((rr & 7) << 4))) = zp1;
    }
    __syncthreads();
    const unsigned char* zc = zbuf + (n & 1) * 16384;
    if (lhi < 2){
      #pragma unroll
      for (int hh = 0; hh < 2; ++hh){
        int ch = w * 32 + hh * 16 + cl;           // h column 0..255
        #pragma unroll
        for (int reg = 0; reg < 4; ++reg){
          int rr = lhi * 4 + reg;                 // row 0..7
          const unsigned char* zr = zc + rr * 2048;
          int sw = (rr & 7) << 4;
          float zi = b2f(*(const unsigned short*)(zr + (((0 * 256 + ch) * 2) ^ sw))) + (float)acc[0 + hh][reg] * s_comb;
          float zf = b2f(*(const unsigned short*)(zr + (((1 * 256 + ch) * 2) ^ sw))) + (float)acc[2 + hh][reg] * s_comb;
          float zg = b2f(*(const unsigned short*)(zr + (((2 * 256 + ch) * 2) ^ sw))) + (float)acc[4 + hh][reg] * s_comb;
          float zo = b2f(*(const unsigned short*)(zr + (((3 * 256 + ch) * 2) ^ sw))) + (float)acc[6 + hh][reg] * s_comb;
          float cv = fsig(zf) * cst[hh * 4 + reg] + fsig(zi) * ftanh(zg);
          cst[hh * 4 + reg] = cv;
          float hv = fsig(zo) * ftanh(cv);
          hbf[rr * 256 + (ch ^ ((rr & 7) << 3))] = (signed char)__float2int_rn(hv * 127.0f);
          if (n == 63) hm[(size_t)(b0 + rr) * 256 + ch] = hv;
        }
      }
    }
    __syncthreads();
  }
}

// ---------------------------------------------------------------------------
extern "C" void kernel_launch(void* const* d_in, const int* in_sizes, int n_in,
                              void* d_out, int out_size, void* d_ws, size_t ws_size,
                              hipStream_t stream){
  const float* x      = (const float*)d_in[0];
  const float* slots  = (const float*)d_in[2];
  const float* cum    = (const float*)d_in[3];
  const float* delta  = (const float*)d_in[4];
  const int*   filled = (const int*)d_in[5];
  const float* Wq  = (const float*)d_in[6];
  const float* Wk  = (const float*)d_in[7];
  const float* Wv  = (const float*)d_in[8];
  const float* bv  = (const float*)d_in[9];
  const float* wih = (const float*)d_in[10];
  const float* whh = (const float*)d_in[11];
  const float* bih = (const float*)d_in[12];
  const float* bhh = (const float*)d_in[13];

  float* out        = (float*)d_out;
  float* hm         = out;                 // (B,H)    524288
  float* slots_out  = out + 524288;        // (B,N,D)  33554432
  float* cum_out    = out + 34078720;      // (B,N,D)  33554432
  float* delta_out  = out + 67633152;      // (B,N)    131072
  float* filled_out = out + 67764224;      // (B,N)    131072

  char* ws = (char*)d_ws;
  int*            idx_ws  = (int*)ws;                                  // 8KB
  float*          v_ws    = (float*)(ws + 8192);                       // 2MB
  float*          bias    = (float*)(ws + 2105344);                    // 4KB
  float*          wlast   = (float*)(ws + 2109440);                    // 4KB
  unsigned short* wfB     = (unsigned short*)(ws + 2113536);           // 1MB
  signed char*    wfrag8  = (signed char*)(ws + 3162112);              // 256KB
  unsigned short* z0      = (unsigned short*)(ws + 3686400);           // 256MB

  k_prep<<<dim3(2048), dim3(256), 0, stream>>>(wih, whh, bih, bhh, wfB, wfrag8, bias, wlast);
  k_route<<<dim3(2048), dim3(256), 0, stream>>>(x, slots, delta, filled, Wq, Wk, Wv, bv,
                                                idx_ws, v_ws, delta_out, filled_out);
  k_scatter<<<dim3(32768), dim3(256), 0, stream>>>(x, slots, cum, idx_ws, v_ws,
                                                   slots_out, cum_out);
  k_gemm<<<dim3(8192), dim3(256), 0, stream>>>(slots_out, cum_out, delta_out,
                                               wfB, wlast, bias, z0);
  k_lstm<<<dim3(256), dim3(512), 36864, stream>>>(z0, wfrag8, hm);
}

// Round 11
// 776.692 us; speedup vs baseline: 1.3159x; 1.3159x over previous
//
#include <hip/hip_runtime.h>
#include <hip/hip_bf16.h>
#include <cstdint>
#include <cstddef>

// B=2048, D=256, H=256, N=64, F=513, 4H=1024

typedef short s16x8 __attribute__((ext_vector_type(8)));
typedef float f32x4 __attribute__((ext_vector_type(4)));
typedef int   i32x4 __attribute__((ext_vector_type(4)));

static __device__ __forceinline__ unsigned short f2b(float f){
  union{float f; unsigned int u;} v; v.f = f;
  unsigned int r = v.u + 0x7fffu + ((v.u >> 16) & 1u);   // RNE
  return (unsigned short)(r >> 16);
}
static __device__ __forceinline__ float b2f(unsigned short h){
  union{unsigned int u; float f;} v; v.u = ((unsigned int)h) << 16; return v.f;
}
static __device__ __forceinline__ unsigned int pack2(float a, float b){
  return (unsigned int)f2b(a) | ((unsigned int)f2b(b) << 16);
}
static __device__ __forceinline__ float fsig(float x){ return 1.0f / (1.0f + __expf(-x)); }
static __device__ __forceinline__ float ftanh(float x){ return 2.0f / (1.0f + __expf(-2.0f * x)) - 1.0f; }
static __device__ __forceinline__ float wred(float p){
  p += __shfl_down(p, 32); p += __shfl_down(p, 16); p += __shfl_down(p, 8);
  p += __shfl_down(p, 4);  p += __shfl_down(p, 2);  p += __shfl_down(p, 1);
  return p;
}
// async global->LDS, 16 B per lane; lds base wave-uniform, global src per-lane
static __device__ __forceinline__ void gload16(const void* g, void* lds){
  __builtin_amdgcn_global_load_lds(
      (const __attribute__((address_space(1))) unsigned int*)g,
      (__attribute__((address_space(3))) unsigned int*)lds, 16, 0, 0);
}

#define WSCALE (0.30f / 127.0f)      // W_hh i8 scale

// ---------------------------------------------------------------------------
// K0: weight prep. wfB: W_ih bf16 B-fragments, kt-major (frag = kt*64 + ct).
// wfrag8: W_hh int8 B-fragments for k_lstm. bias = b_ih+b_hh; wlast = W_ih[:,512].
// ---------------------------------------------------------------------------
__global__ __launch_bounds__(256) void k_prep(
    const float* __restrict__ wih, const float* __restrict__ whh,
    const float* __restrict__ bih, const float* __restrict__ bhh,
    unsigned short* __restrict__ wfB, signed char* __restrict__ wfrag8,
    float* __restrict__ bias, float* __restrict__ wlast){
  int id = blockIdx.x * 256 + threadIdx.x;          // grid covers 524288
  { // wfB: 1024 frags * 512 entries, kt-major
    int frag = id >> 9;
    int l = (id >> 3) & 63;
    int j = id & 7;
    int kt = frag >> 6, ct = frag & 63;
    int col = ct * 16 + (l & 15);
    int k   = kt * 32 + (l >> 4) * 8 + j;
    wfB[id] = f2b(wih[col * 513 + k]);
  }
  if (id < 262144){ // wfrag8: 512 frags * 512 entries, int8
    int frag = id >> 9;
    int lane = (id >> 3) & 63;
    int j    = id & 7;
    int w  = frag >> 6;
    int kt = (frag >> 3) & 7;
    int nt = frag & 7;
    int g  = nt >> 1, hh = nt & 1;
    int colg = g * 256 + w * 32 + hh * 16 + (lane & 15);
    int k    = kt * 32 + (lane >> 4) * 8 + j;
    int q = __float2int_rn(whh[colg * 256 + k] * (1.0f / WSCALE));
    q = q > 127 ? 127 : (q < -127 ? -127 : q);
    wfrag8[frag * 512 + lane * 8 + j] = (signed char)q;
  }
  if (id < 1024){
    bias[id]  = bih[id] + bhh[id];
    wlast[id] = wih[id * 513 + 512];
  }
}

// ---------------------------------------------------------------------------
// K1: routing (fast path = first empty slot via ballot; sims fallback kept).
// ---------------------------------------------------------------------------
__global__ __launch_bounds__(256) void k_route(
    const float* __restrict__ x, const float* __restrict__ slots,
    const float* __restrict__ delta, const int* __restrict__ filled,
    const float* __restrict__ Wq, const float* __restrict__ Wk,
    const float* __restrict__ Wv, const float* __restrict__ bv,
    int* __restrict__ idx_ws, float* __restrict__ v_ws,
    float* __restrict__ delta_out, float* __restrict__ filled_out){
  int b = blockIdx.x, tid = threadIdx.x, l = tid & 63, w = tid >> 6;
  __shared__ float xs[256], qs[256], qks[256], sims[64];
  __shared__ int sidx;
  xs[tid] = x[b * 256 + tid];
  if (tid < 64){
    unsigned long long em = __ballot(filled[b * 64 + tid] == 0);
    if (tid == 0) sidx = em ? (int)__builtin_ctzll(em) : -1;
  }
  __syncthreads();
  for (int t = 0; t < 64; ++t){
    int h = w * 64 + t;
    float pv = 0.f;
    #pragma unroll
    for (int j2 = 0; j2 < 4; ++j2)
      pv += Wv[h * 256 + l + 64 * j2] * xs[l + 64 * j2];
    pv = wred(pv);
    if (l == 0) v_ws[b * 256 + h] = pv + bv[h];
  }
  if (sidx < 0){           // rare fallback: content-based argmax
    for (int t = 0; t < 64; ++t){
      int h = w * 64 + t;
      float p = 0.f;
      #pragma unroll
      for (int j2 = 0; j2 < 4; ++j2)
        p += Wq[h * 256 + l + 64 * j2] * xs[l + 64 * j2];
      p = wred(p);
      if (l == 0) qs[h] = p;
    }
    __syncthreads();
    {
      int d = tid; float p = 0.f;
      for (int h = 0; h < 256; ++h) p += qs[h] * Wk[h * 256 + d];
      qks[d] = p;
    }
    __syncthreads();
    for (int t = 0; t < 16; ++t){
      int n = w * 16 + t;
      float p = 0.f;
      #pragma unroll
      for (int j2 = 0; j2 < 4; ++j2)
        p += slots[(size_t)(b * 64 + n) * 256 + l + 64 * j2] * qks[l + 64 * j2];
      p = wred(p);
      if (l == 0) sims[n] = p;
    }
    __syncthreads();
    if (tid == 0){
      int ic = 0; float best = sims[0];
      for (int n = 1; n < 64; ++n) if (sims[n] > best){ best = sims[n]; ic = n; }
      sidx = ic;
    }
  }
  __syncthreads();
  int id = sidx;
  if (tid == 0) idx_ws[b] = id;
  if (tid < 64){
    int n = tid; bool sel = (n == id);
    delta_out[b * 64 + n]  = sel ? 0.0f : (delta[b * 64 + n] + 1.0f);
    filled_out[b * 64 + n] = (sel || filled[b * 64 + n] != 0) ? 1.0f : 0.0f;
  }
}

// ---------------------------------------------------------------------------
// K2 v2: scatter/copy + bf16 A production.
// Block = 4 rows x 64 lanes. Lane l<32: slots granule k=l*8 (8 floats);
// l>=32: cum granule k=(l-32)*8 with +x fold. Writes fp32 outputs AND the
// bf16 GEMM input abf[m][k] (row = [slots|cum], 512 bf16 = 1KB contiguous).
// ---------------------------------------------------------------------------
__global__ __launch_bounds__(256) void k_scatter(
    const float* __restrict__ x, const float* __restrict__ slots,
    const float* __restrict__ cum, const int* __restrict__ idx_ws,
    const float* __restrict__ v_ws,
    float* __restrict__ slots_out, float* __restrict__ cum_out,
    unsigned short* __restrict__ abf){
  int rg = threadIdx.x >> 6, l = threadIdx.x & 63;
  int row = blockIdx.x * 4 + rg;
  int b = row >> 6, n = row & 63;
  bool sel = (n == idx_ws[b]);
  float4 f0, f1;
  if (l < 32){
    int k0 = l * 8;
    const float* src = sel ? (v_ws + (size_t)b * 256 + k0)
                           : (slots + (size_t)row * 256 + k0);
    f0 = ((const float4*)src)[0]; f1 = ((const float4*)src)[1];
    float4* d = (float4*)(slots_out + (size_t)row * 256 + k0);
    d[0] = f0; d[1] = f1;
  } else {
    int k0 = (l - 32) * 8;
    const float4* xp = (const float4*)(x + (size_t)b * 256 + k0);
    float4 x0 = xp[0], x1 = xp[1];
    if (sel){ f0 = x0; f1 = x1; }
    else {
      const float4* cp = (const float4*)(cum + (size_t)row * 256 + k0);
      f0 = cp[0]; f1 = cp[1];
      f0.x += x0.x; f0.y += x0.y; f0.z += x0.z; f0.w += x0.w;
      f1.x += x1.x; f1.y += x1.y; f1.z += x1.z; f1.w += x1.w;
    }
    float4* d = (float4*)(cum_out + (size_t)row * 256 + k0);
    d[0] = f0; d[1] = f1;
  }
  uint4 q;
  q.x = pack2(f0.x, f0.y); q.y = pack2(f0.z, f0.w);
  q.z = pack2(f1.x, f1.y); q.w = pack2(f1.z, f1.w);
  *(uint4*)(abf + (size_t)row * 512 + l * 8) = q;   // l*8 covers both halves
}

// ---------------------------------------------------------------------------
// K3 v11: PURE bf16 GEMM (exact m97 shape). Z0 = abf @ W_ih^T + eps.
// A and B both via global_load_lds double-buffers (async DMA, per-lane
// sources, linear LDS dest). A-tile [kq 0..3][128 rows]x16B: fragment =
// single conflict-free ds_read_b128. No conversion, no per-lane loads,
// one barrier per K-step. 32 KB LDS -> 5 blocks/CU; grid 8192 XCD-chunked.
// z0 step-major: z0[(n*2048 + b)*1024 + gc] (bf16).
// ---------------------------------------------------------------------------
__global__ __launch_bounds__(256) void k_gemm(
    const unsigned short* __restrict__ abf,
    const float* __restrict__ dlt,
    const unsigned short* __restrict__ wfB,
    const float* __restrict__ wlast, const float* __restrict__ bias,
    unsigned short* __restrict__ z0){
  __shared__ unsigned char L[32768];
  int tid = threadIdx.x, l = tid & 63, w = tid >> 6;
  int bid = blockIdx.x;
  int gw = (bid & 7) * 1024 + (bid >> 3);        // XCD-chunked bijection
  int n_idx = gw & 7, m_idx = gw >> 3;
  int m0 = m_idx * 128, n0 = n_idx * 128, bA = m0 >> 6;
  int wm = w & 1, wn = w >> 1, cl = l & 15, lhi = l >> 4;
  int arow = tid & 127, akq = tid >> 7;          // staging: thread -> (kq,row)

  auto stageA = [&](int kt, int abase){
    const unsigned short* s = abf + (size_t)(m0 + arow) * 512 + kt * 32 + akq * 8;
    gload16(s,      L + abase + w * 1024);          // kq 0/1
    gload16(s + 16, L + abase + 4096 + w * 1024);   // kq 2/3
  };
  auto stageB = [&](int kt, int bbase){
    const unsigned short* s = wfB + ((size_t)(kt * 64 + n_idx * 8 + w * 2)) * 512 + l * 8;
    gload16(s, L + bbase + w * 2048);
    gload16(s + 512, L + bbase + w * 2048 + 1024);
  };

  f32x4 acc[4][4];
  #pragma unroll
  for (int mi = 0; mi < 4; ++mi)
    #pragma unroll
    for (int ni = 0; ni < 4; ++ni){ f32x4 zr = {0.f,0.f,0.f,0.f}; acc[mi][ni] = zr; }

  stageA(0, 0);
  stageB(0, 16384);
  __syncthreads();

  for (int kt = 0; kt < 16; ++kt){
    int cur = kt & 1, nxt = cur ^ 1;
    if (kt < 15){
      stageA(kt + 1, nxt * 8192);
      stageB(kt + 1, 16384 + nxt * 8192);
    }
    int ab = cur * 8192, bb = 16384 + cur * 8192;
    s16x8 a[4], bf[4];
    #pragma unroll
    for (int mi = 0; mi < 4; ++mi)
      a[mi] = *(const s16x8*)(L + ab + lhi * 2048 + (wm * 64 + mi * 16 + cl) * 16);
    #pragma unroll
    for (int ni = 0; ni < 4; ++ni)
      bf[ni] = *(const s16x8*)(L + bb + (wn * 4 + ni) * 1024 + l * 16);
    #pragma unroll
    for (int ni = 0; ni < 4; ++ni)
      #pragma unroll
      for (int mi = 0; mi < 4; ++mi)
        acc[mi][ni] = __builtin_amdgcn_mfma_f32_16x16x32_bf16(a[mi], bf[ni], acc[mi][ni], 0, 0, 0);
    __syncthreads();
  }

  // epilogue: acc -> L (z-stage, 128 rows x 256 B) -> coalesced z0 stores
  float dv[4][4];
  #pragma unroll
  for (int mi = 0; mi < 4; ++mi)
    #pragma unroll
    for (int reg = 0; reg < 4; ++reg)
      dv[mi][reg] = dlt[(bA + wm) * 64 + mi * 16 + lhi * 4 + reg];
  #pragma unroll
  for (int mi = 0; mi < 4; ++mi)
    #pragma unroll
    for (int reg = 0; reg < 4; ++reg){
      int row = wm * 64 + mi * 16 + lhi * 4 + reg;
      #pragma unroll
      for (int ni = 0; ni < 4; ++ni){
        int col = wn * 64 + ni * 16 + cl;
        int gc = n0 + col;
        float val = acc[mi][ni][reg] + dv[mi][reg] * wlast[gc] + bias[gc];
        *(unsigned short*)(L + row * 256 + ((col * 2) ^ ((row & 7) << 4))) = f2b(val);
      }
    }
  __syncthreads();
  #pragma unroll
  for (int rr = 0; rr < 8; ++rr){
    int row = w * 32 + rr * 4 + lhi;
    int bq = bA + (row >> 6), nq = row & 63;
    uint4 v = *(const uint4*)(L + row * 256 + ((cl * 16) ^ ((row & 7) << 4)));
    *(uint4*)(z0 + ((size_t)nq * 2048 + bq) * 1024 + n0 + cl * 8) = v;
  }
}

// ---------------------------------------------------------------------------
// K4 v6: recurrent LSTM, int8 register-resident W_hh, 256 blocks x 8 rows.
// ---------------------------------------------------------------------------
__global__ __launch_bounds__(512) void k_lstm(
    const unsigned short* __restrict__ z0,
    const signed char* __restrict__ wfrag8,
    float* __restrict__ hm){
  extern __shared__ unsigned char smem[];
  unsigned char* zbuf = smem;                 // 2 x 16 KB
  unsigned char* hbf  = smem + 32768;         // 16 x 256 int8 = 4 KB, swizzled
  int tid = threadIdx.x, l = tid & 63, w = tid >> 6;
  int cl = l & 15, lhi = l >> 4;
  int b0 = blockIdx.x * 8;

  for (int i = tid; i < 1024; i += 512) ((unsigned int*)hbf)[i] = 0u;

  // resident weights: 64 frags x 8 B (128 VGPRs)
  long long wpin[64];
  #pragma unroll
  for (int f = 0; f < 64; ++f)
    wpin[f] = *(const long long*)(wfrag8 + ((size_t)w * 64 + f) * 512 + l * 8);

  // prologue: z slice n=0 -> buf0 (16B-granule row-XOR swizzle)
  {
    const uint4* src = (const uint4*)(z0 + (size_t)b0 * 1024);
    int rr = tid >> 6, off = (tid & 63) * 32;
    unsigned char* base = zbuf + rr * 2048;
    *(uint4*)(base + ((off)      ^ ((rr & 7) << 4))) = src[tid * 2];
    *(uint4*)(base + ((off + 16) ^ ((rr & 7) << 4))) = src[tid * 2 + 1];
  }
  float cst[8];
  #pragma unroll
  for (int i = 0; i < 8; ++i) cst[i] = 0.f;
  const float s_comb = WSCALE / 127.0f;       // acc_i32 -> z_hh f32
  __syncthreads();

  for (int n = 0; n < 64; ++n){
    uint4 zp0, zp1;
    if (n < 63){
      const uint4* src = (const uint4*)(z0 + ((size_t)(n + 1) * 2048 + b0) * 1024);
      zp0 = src[tid * 2]; zp1 = src[tid * 2 + 1];
    }
    i32x4 acc[8];
    #pragma unroll
    for (int nt = 0; nt < 8; ++nt){ i32x4 zr = {0, 0, 0, 0}; acc[nt] = zr; }
    #pragma unroll
    for (int kt = 0; kt < 8; ++kt){
      int byteo = cl * 256 + ((kt * 32 + lhi * 8) ^ ((cl & 7) << 3));
      long long a = *(const long long*)(hbf + byteo);
      #pragma unroll
      for (int nt = 0; nt < 8; ++nt)
        acc[nt] = __builtin_amdgcn_mfma_i32_16x16x32_i8(a, wpin[kt * 8 + nt], acc[nt], 0, 0, 0);
    }
    if (n < 63){
      int rr = tid >> 6, off = (tid & 63) * 32;
      unsigned char* base = zbuf + ((n + 1) & 1) * 16384 + rr * 2048;
      *(uint4*)(base + ((off)      ^ ((rr & 7) << 4))) = zp0;
      *(uint4*)(base + ((off + 16) ^ ((rr & 7) << 4))) = zp1;
    }
    __syncthreads();
    const unsigned char* zc = zbuf + (n & 1) * 16384;
    if (lhi < 2){
      #pragma unroll
      for (int hh = 0; hh < 2; ++hh){
        int ch = w * 32 + hh * 16 + cl;           // h column 0..255
        #pragma unroll
        for (int reg = 0; reg < 4; ++reg){
          int rr = lhi * 4 + reg;                 // row 0..7
          const unsigned char* zr = zc + rr * 2048;
          int sw = (rr & 7) << 4;
          float zi = b2f(*(const unsigned short*)(zr + (((0 * 256 + ch) * 2) ^ sw))) + (float)acc[0 + hh][reg] * s_comb;
          float zf = b2f(*(const unsigned short*)(zr + (((1 * 256 + ch) * 2) ^ sw))) + (float)acc[2 + hh][reg] * s_comb;
          float zg = b2f(*(const unsigned short*)(zr + (((2 * 256 + ch) * 2) ^ sw))) + (float)acc[4 + hh][reg] * s_comb;
          float zo = b2f(*(const unsigned short*)(zr + (((3 * 256 + ch) * 2) ^ sw))) + (float)acc[6 + hh][reg] * s_comb;
          float cv = fsig(zf) * cst[hh * 4 + reg] + fsig(zi) * ftanh(zg);
          cst[hh * 4 + reg] = cv;
          float hv = fsig(zo) * ftanh(cv);
          hbf[rr * 256 + (ch ^ ((rr & 7) << 3))] = (signed char)__float2int_rn(hv * 127.0f);
          if (n == 63) hm[(size_t)(b0 + rr) * 256 + ch] = hv;
        }
      }
    }
    __syncthreads();
  }
}

// ---------------------------------------------------------------------------
extern "C" void kernel_launch(void* const* d_in, const int* in_sizes, int n_in,
                              void* d_out, int out_size, void* d_ws, size_t ws_size,
                              hipStream_t stream){
  const float* x      = (const float*)d_in[0];
  const float* slots  = (const float*)d_in[2];
  const float* cum    = (const float*)d_in[3];
  const float* delta  = (const float*)d_in[4];
  const int*   filled = (const int*)d_in[5];
  const float* Wq  = (const float*)d_in[6];
  const float* Wk  = (const float*)d_in[7];
  const float* Wv  = (const float*)d_in[8];
  const float* bv  = (const float*)d_in[9];
  const float* wih = (const float*)d_in[10];
  const float* whh = (const float*)d_in[11];
  const float* bih = (const float*)d_in[12];
  const float* bhh = (const float*)d_in[13];

  float* out        = (float*)d_out;
  float* hm         = out;                 // (B,H)    524288
  float* slots_out  = out + 524288;        // (B,N,D)  33554432
  float* cum_out    = out + 34078720;      // (B,N,D)  33554432
  float* delta_out  = out + 67633152;      // (B,N)    131072
  float* filled_out = out + 67764224;      // (B,N)    131072

  char* ws = (char*)d_ws;
  int*            idx_ws  = (int*)ws;                                  // 8KB
  float*          v_ws    = (float*)(ws + 8192);                       // 2MB
  float*          bias    = (float*)(ws + 2105344);                    // 4KB
  float*          wlast   = (float*)(ws + 2109440);                    // 4KB
  unsigned short* wfB     = (unsigned short*)(ws + 2113536);           // 1MB
  signed char*    wfrag8  = (signed char*)(ws + 3162112);              // 256KB
  unsigned short* abf     = (unsigned short*)(ws + 3686400);           // 128MB
  unsigned short* z0      = (unsigned short*)(ws + 3686400 + 134217728); // 256MB

  k_prep<<<dim3(2048), dim3(256), 0, stream>>>(wih, whh, bih, bhh, wfB, wfrag8, bias, wlast);
  k_route<<<dim3(2048), dim3(256), 0, stream>>>(x, slots, delta, filled, Wq, Wk, Wv, bv,
                                                idx_ws, v_ws, delta_out, filled_out);
  k_scatter<<<dim3(32768), dim3(256), 0, stream>>>(x, slots, cum, idx_ws, v_ws,
                                                   slots_out, cum_out, abf);
  k_gemm<<<dim3(8192), dim3(256), 0, stream>>>(abf, delta_out,
                                               wfB, wlast, bias, z0);
  k_lstm<<<dim3(256), dim3(512), 36864, stream>>>(z0, wfrag8, hm);
}

// Round 12
// 736.338 us; speedup vs baseline: 1.3881x; 1.0548x over previous
//
#include <hip/hip_runtime.h>
#include <hip/hip_bf16.h>
#include <cstdint>
#include <cstddef>

// B=2048, D=256, H=256, N=64, F=513, 4H=1024

typedef short s16x8 __attribute__((ext_vector_type(8)));
typedef float f32x4 __attribute__((ext_vector_type(4)));
typedef int   i32x4 __attribute__((ext_vector_type(4)));

static __device__ __forceinline__ unsigned short f2b(float f){
  union{float f; unsigned int u;} v; v.f = f;
  unsigned int r = v.u + 0x7fffu + ((v.u >> 16) & 1u);   // RNE
  return (unsigned short)(r >> 16);
}
static __device__ __forceinline__ float b2f(unsigned short h){
  union{unsigned int u; float f;} v; v.u = ((unsigned int)h) << 16; return v.f;
}
static __device__ __forceinline__ unsigned int pack2(float a, float b){
  return (unsigned int)f2b(a) | ((unsigned int)f2b(b) << 16);
}
static __device__ __forceinline__ float fsig(float x){ return 1.0f / (1.0f + __expf(-x)); }
static __device__ __forceinline__ float ftanh(float x){ return 2.0f / (1.0f + __expf(-2.0f * x)) - 1.0f; }
static __device__ __forceinline__ float wred(float p){
  p += __shfl_down(p, 32); p += __shfl_down(p, 16); p += __shfl_down(p, 8);
  p += __shfl_down(p, 4);  p += __shfl_down(p, 2);  p += __shfl_down(p, 1);
  return p;
}
// async global->LDS, 16 B per lane; lds base wave-uniform, global src per-lane
static __device__ __forceinline__ void gload16(const void* g, void* lds){
  __builtin_amdgcn_global_load_lds(
      (const __attribute__((address_space(1))) unsigned int*)g,
      (__attribute__((address_space(3))) unsigned int*)lds, 16, 0, 0);
}

#define WSCALE (0.30f / 127.0f)      // W_hh i8 scale

// ---------------------------------------------------------------------------
// K0: weight prep. wfB: W_ih bf16 B-fragments, kt-major (frag = kt*64 + ct).
// wfrag8: W_hh int8 B-fragments for k_lstm. bias = b_ih+b_hh; wlast = W_ih[:,512].
// ---------------------------------------------------------------------------
__global__ __launch_bounds__(256) void k_prep(
    const float* __restrict__ wih, const float* __restrict__ whh,
    const float* __restrict__ bih, const float* __restrict__ bhh,
    unsigned short* __restrict__ wfB, signed char* __restrict__ wfrag8,
    float* __restrict__ bias, float* __restrict__ wlast){
  int id = blockIdx.x * 256 + threadIdx.x;          // grid covers 524288
  { // wfB: 1024 frags * 512 entries, kt-major
    int frag = id >> 9;
    int l = (id >> 3) & 63;
    int j = id & 7;
    int kt = frag >> 6, ct = frag & 63;
    int col = ct * 16 + (l & 15);
    int k   = kt * 32 + (l >> 4) * 8 + j;
    wfB[id] = f2b(wih[col * 513 + k]);
  }
  if (id < 262144){ // wfrag8: 512 frags * 512 entries, int8
    int frag = id >> 9;
    int lane = (id >> 3) & 63;
    int j    = id & 7;
    int w  = frag >> 6;
    int kt = (frag >> 3) & 7;
    int nt = frag & 7;
    int g  = nt >> 1, hh = nt & 1;
    int colg = g * 256 + w * 32 + hh * 16 + (lane & 15);
    int k    = kt * 32 + (lane >> 4) * 8 + j;
    int q = __float2int_rn(whh[colg * 256 + k] * (1.0f / WSCALE));
    q = q > 127 ? 127 : (q < -127 ? -127 : q);
    wfrag8[frag * 512 + lane * 8 + j] = (signed char)q;
  }
  if (id < 1024){
    bias[id]  = bih[id] + bhh[id];
    wlast[id] = wih[id * 513 + 512];
  }
}

// ---------------------------------------------------------------------------
// K1: routing (fast path = first empty slot via ballot; sims fallback kept).
// ---------------------------------------------------------------------------
__global__ __launch_bounds__(256) void k_route(
    const float* __restrict__ x, const float* __restrict__ slots,
    const float* __restrict__ delta, const int* __restrict__ filled,
    const float* __restrict__ Wq, const float* __restrict__ Wk,
    const float* __restrict__ Wv, const float* __restrict__ bv,
    int* __restrict__ idx_ws, float* __restrict__ v_ws,
    float* __restrict__ delta_out, float* __restrict__ filled_out){
  int b = blockIdx.x, tid = threadIdx.x, l = tid & 63, w = tid >> 6;
  __shared__ float xs[256], qs[256], qks[256], sims[64];
  __shared__ int sidx;
  xs[tid] = x[b * 256 + tid];
  if (tid < 64){
    unsigned long long em = __ballot(filled[b * 64 + tid] == 0);
    if (tid == 0) sidx = em ? (int)__builtin_ctzll(em) : -1;
  }
  __syncthreads();
  for (int t = 0; t < 64; ++t){
    int h = w * 64 + t;
    float pv = 0.f;
    #pragma unroll
    for (int j2 = 0; j2 < 4; ++j2)
      pv += Wv[h * 256 + l + 64 * j2] * xs[l + 64 * j2];
    pv = wred(pv);
    if (l == 0) v_ws[b * 256 + h] = pv + bv[h];
  }
  if (sidx < 0){           // rare fallback: content-based argmax
    for (int t = 0; t < 64; ++t){
      int h = w * 64 + t;
      float p = 0.f;
      #pragma unroll
      for (int j2 = 0; j2 < 4; ++j2)
        p += Wq[h * 256 + l + 64 * j2] * xs[l + 64 * j2];
      p = wred(p);
      if (l == 0) qs[h] = p;
    }
    __syncthreads();
    {
      int d = tid; float p = 0.f;
      for (int h = 0; h < 256; ++h) p += qs[h] * Wk[h * 256 + d];
      qks[d] = p;
    }
    __syncthreads();
    for (int t = 0; t < 16; ++t){
      int n = w * 16 + t;
      float p = 0.f;
      #pragma unroll
      for (int j2 = 0; j2 < 4; ++j2)
        p += slots[(size_t)(b * 64 + n) * 256 + l + 64 * j2] * qks[l + 64 * j2];
      p = wred(p);
      if (l == 0) sims[n] = p;
    }
    __syncthreads();
    if (tid == 0){
      int ic = 0; float best = sims[0];
      for (int n = 1; n < 64; ++n) if (sims[n] > best){ best = sims[n]; ic = n; }
      sidx = ic;
    }
  }
  __syncthreads();
  int id = sidx;
  if (tid == 0) idx_ws[b] = id;
  if (tid < 64){
    int n = tid; bool sel = (n == id);
    delta_out[b * 64 + n]  = sel ? 0.0f : (delta[b * 64 + n] + 1.0f);
    filled_out[b * 64 + n] = (sel || filled[b * 64 + n] != 0) ? 1.0f : 0.0f;
  }
}

// ---------------------------------------------------------------------------
// K2 v2: scatter/copy + bf16 A production (unchanged from R11).
// ---------------------------------------------------------------------------
__global__ __launch_bounds__(256) void k_scatter(
    const float* __restrict__ x, const float* __restrict__ slots,
    const float* __restrict__ cum, const int* __restrict__ idx_ws,
    const float* __restrict__ v_ws,
    float* __restrict__ slots_out, float* __restrict__ cum_out,
    unsigned short* __restrict__ abf){
  int rg = threadIdx.x >> 6, l = threadIdx.x & 63;
  int row = blockIdx.x * 4 + rg;
  int b = row >> 6, n = row & 63;
  bool sel = (n == idx_ws[b]);
  float4 f0, f1;
  if (l < 32){
    int k0 = l * 8;
    const float* src = sel ? (v_ws + (size_t)b * 256 + k0)
                           : (slots + (size_t)row * 256 + k0);
    f0 = ((const float4*)src)[0]; f1 = ((const float4*)src)[1];
    float4* d = (float4*)(slots_out + (size_t)row * 256 + k0);
    d[0] = f0; d[1] = f1;
  } else {
    int k0 = (l - 32) * 8;
    const float4* xp = (const float4*)(x + (size_t)b * 256 + k0);
    float4 x0 = xp[0], x1 = xp[1];
    if (sel){ f0 = x0; f1 = x1; }
    else {
      const float4* cp = (const float4*)(cum + (size_t)row * 256 + k0);
      f0 = cp[0]; f1 = cp[1];
      f0.x += x0.x; f0.y += x0.y; f0.z += x0.z; f0.w += x0.w;
      f1.x += x1.x; f1.y += x1.y; f1.z += x1.z; f1.w += x1.w;
    }
    float4* d = (float4*)(cum_out + (size_t)row * 256 + k0);
    d[0] = f0; d[1] = f1;
  }
  uint4 q;
  q.x = pack2(f0.x, f0.y); q.y = pack2(f0.z, f0.w);
  q.z = pack2(f1.x, f1.y); q.w = pack2(f1.z, f1.w);
  *(uint4*)(abf + (size_t)row * 512 + l * 8) = q;   // l*8 covers both halves
}

// ---------------------------------------------------------------------------
// K3 v12: pure bf16 GEMM with T4 counted-vmcnt depth-2 pipeline.
// 3 LDS buffers per operand; per kt: issue stage(kt+2) [4 DMA/wave,
// symmetric across waves] -> s_waitcnt vmcnt(8) (own tile-kt loads landed)
// -> raw s_barrier -> ds_read+MFMA -> raw s_barrier (WAR). NO vmcnt(0)
// drain in the main loop; epilogue drains 8->4->0. 48 KB LDS.
// LDS: A bufs @0/8192/16384; B bufs @24576/32768/40960.
// z0 step-major: z0[(n*2048 + b)*1024 + gc] (bf16).
// ---------------------------------------------------------------------------
__global__ __launch_bounds__(256) void k_gemm(
    const unsigned short* __restrict__ abf,
    const float* __restrict__ dlt,
    const unsigned short* __restrict__ wfB,
    const float* __restrict__ wlast, const float* __restrict__ bias,
    unsigned short* __restrict__ z0){
  __shared__ unsigned char L[49152];
  int tid = threadIdx.x, l = tid & 63, w = tid >> 6;
  int bid = blockIdx.x;
  int gw = (bid & 7) * 1024 + (bid >> 3);        // XCD-chunked bijection
  int n_idx = gw & 7, m_idx = gw >> 3;
  int m0 = m_idx * 128, n0 = n_idx * 128, bA = m0 >> 6;
  int wm = w & 1, wn = w >> 1, cl = l & 15, lhi = l >> 4;
  int arow = tid & 127, akq = tid >> 7;          // staging: thread -> (kq,row)

  auto stageA = [&](int kt, int abase){
    const unsigned short* s = abf + (size_t)(m0 + arow) * 512 + kt * 32 + akq * 8;
    gload16(s,      L + abase + w * 1024);          // kq 0/1
    gload16(s + 16, L + abase + 4096 + w * 1024);   // kq 2/3
  };
  auto stageB = [&](int kt, int bbase){
    const unsigned short* s = wfB + ((size_t)(kt * 64 + n_idx * 8 + w * 2)) * 512 + l * 8;
    gload16(s, L + bbase + w * 2048);
    gload16(s + 512, L + bbase + w * 2048 + 1024);
  };

  f32x4 acc[4][4];
  #pragma unroll
  for (int mi = 0; mi < 4; ++mi)
    #pragma unroll
    for (int ni = 0; ni < 4; ++ni){ f32x4 zr = {0.f,0.f,0.f,0.f}; acc[mi][ni] = zr; }

  // prologue: stage tiles 0 and 1 (8 outstanding DMA/wave, issue order matters)
  stageA(0, 0);      stageB(0, 24576);
  stageA(1, 8192);   stageB(1, 32768);

  #pragma unroll
  for (int kt = 0; kt < 16; ++kt){
    if (kt < 14){
      int nb = (kt + 2) % 3;
      stageA(kt + 2, nb * 8192);
      stageB(kt + 2, 24576 + nb * 8192);
    }
    // counted wait: tile kt's 4 DMAs (per wave) have landed; never drain to 0
    if (kt < 14)       asm volatile("s_waitcnt vmcnt(8)" ::: "memory");
    else if (kt == 14) asm volatile("s_waitcnt vmcnt(4)" ::: "memory");
    else               asm volatile("s_waitcnt vmcnt(0)" ::: "memory");
    __builtin_amdgcn_s_barrier();                // all waves' tile-kt landed
    __builtin_amdgcn_sched_barrier(0);
    int ab = (kt % 3) * 8192, bb = 24576 + (kt % 3) * 8192;
    s16x8 a[4], bf[4];
    #pragma unroll
    for (int mi = 0; mi < 4; ++mi)
      a[mi] = *(const s16x8*)(L + ab + lhi * 2048 + (wm * 64 + mi * 16 + cl) * 16);
    #pragma unroll
    for (int ni = 0; ni < 4; ++ni)
      bf[ni] = *(const s16x8*)(L + bb + (wn * 4 + ni) * 1024 + l * 16);
    #pragma unroll
    for (int ni = 0; ni < 4; ++ni)
      #pragma unroll
      for (int mi = 0; mi < 4; ++mi)
        acc[mi][ni] = __builtin_amdgcn_mfma_f32_16x16x32_bf16(a[mi], bf[ni], acc[mi][ni], 0, 0, 0);
    __builtin_amdgcn_sched_barrier(0);
    __builtin_amdgcn_s_barrier();                // reads done before buf reuse
  }

  // epilogue: acc -> L (z-stage, 128 rows x 256 B) -> coalesced z0 stores
  float dv[4][4];
  #pragma unroll
  for (int mi = 0; mi < 4; ++mi)
    #pragma unroll
    for (int reg = 0; reg < 4; ++reg)
      dv[mi][reg] = dlt[(bA + wm) * 64 + mi * 16 + lhi * 4 + reg];
  #pragma unroll
  for (int mi = 0; mi < 4; ++mi)
    #pragma unroll
    for (int reg = 0; reg < 4; ++reg){
      int row = wm * 64 + mi * 16 + lhi * 4 + reg;
      #pragma unroll
      for (int ni = 0; ni < 4; ++ni){
        int col = wn * 64 + ni * 16 + cl;
        int gc = n0 + col;
        float val = acc[mi][ni][reg] + dv[mi][reg] * wlast[gc] + bias[gc];
        *(unsigned short*)(L + row * 256 + ((col * 2) ^ ((row & 7) << 4))) = f2b(val);
      }
    }
  __syncthreads();
  #pragma unroll
  for (int rr = 0; rr < 8; ++rr){
    int row = w * 32 + rr * 4 + lhi;
    int bq = bA + (row >> 6), nq = row & 63;
    uint4 v = *(const uint4*)(L + row * 256 + ((cl * 16) ^ ((row & 7) << 4)));
    *(uint4*)(z0 + ((size_t)nq * 2048 + bq) * 1024 + n0 + cl * 8) = v;
  }
}

// ---------------------------------------------------------------------------
// K4 v6: recurrent LSTM, int8 register-resident W_hh, 256 blocks x 8 rows.
// ---------------------------------------------------------------------------
__global__ __launch_bounds__(512) void k_lstm(
    const unsigned short* __restrict__ z0,
    const signed char* __restrict__ wfrag8,
    float* __restrict__ hm){
  extern __shared__ unsigned char smem[];
  unsigned char* zbuf = smem;                 // 2 x 16 KB
  unsigned char* hbf  = smem + 32768;         // 16 x 256 int8 = 4 KB, swizzled
  int tid = threadIdx.x, l = tid & 63, w = tid >> 6;
  int cl = l & 15, lhi = l >> 4;
  int b0 = blockIdx.x * 8;

  for (int i = tid; i < 1024; i += 512) ((unsigned int*)hbf)[i] = 0u;

  // resident weights: 64 frags x 8 B (128 VGPRs)
  long long wpin[64];
  #pragma unroll
  for (int f = 0; f < 64; ++f)
    wpin[f] = *(const long long*)(wfrag8 + ((size_t)w * 64 + f) * 512 + l * 8);

  // prologue: z slice n=0 -> buf0 (16B-granule row-XOR swizzle)
  {
    const uint4* src = (const uint4*)(z0 + (size_t)b0 * 1024);
    int rr = tid >> 6, off = (tid & 63) * 32;
    unsigned char* base = zbuf + rr * 2048;
    *(uint4*)(base + ((off)      ^ ((rr & 7) << 4))) = src[tid * 2];
    *(uint4*)(base + ((off + 16) ^ ((rr & 7) << 4))) = src[tid * 2 + 1];
  }
  float cst[8];
  #pragma unroll
  for (int i = 0; i < 8; ++i) cst[i] = 0.f;
  const float s_comb = WSCALE / 127.0f;       // acc_i32 -> z_hh f32
  __syncthreads();

  for (int n = 0; n < 64; ++n){
    uint4 zp0, zp1;
    if (n < 63){
      const uint4* src = (const uint4*)(z0 + ((size_t)(n + 1) * 2048 + b0) * 1024);
      zp0 = src[tid * 2]; zp1 = src[tid * 2 + 1];
    }
    i32x4 acc[8];
    #pragma unroll
    for (int nt = 0; nt < 8; ++nt){ i32x4 zr = {0, 0, 0, 0}; acc[nt] = zr; }
    #pragma unroll
    for (int kt = 0; kt < 8; ++kt){
      int byteo = cl * 256 + ((kt * 32 + lhi * 8) ^ ((cl & 7) << 3));
      long long a = *(const long long*)(hbf + byteo);
      #pragma unroll
      for (int nt = 0; nt < 8; ++nt)
        acc[nt] = __builtin_amdgcn_mfma_i32_16x16x32_i8(a, wpin[kt * 8 + nt], acc[nt], 0, 0, 0);
    }
    if (n < 63){
      int rr = tid >> 6, off = (tid & 63) * 32;
      unsigned char* base = zbuf + ((n + 1) & 1) * 16384 + rr * 2048;
      *(uint4*)(base + ((off)      ^ ((rr & 7) << 4))) = zp0;
      *(uint4*)(base + ((off + 16) ^ ((rr & 7) << 4))) = zp1;
    }
    __syncthreads();
    const unsigned char* zc = zbuf + (n & 1) * 16384;
    if (lhi < 2){
      #pragma unroll
      for (int hh = 0; hh < 2; ++hh){
        int ch = w * 32 + hh * 16 + cl;           // h column 0..255
        #pragma unroll
        for (int reg = 0; reg < 4; ++reg){
          int rr = lhi * 4 + reg;                 // row 0..7
          const unsigned char* zr = zc + rr * 2048;
          int sw = (rr & 7) << 4;
          float zi = b2f(*(const unsigned short*)(zr + (((0 * 256 + ch) * 2) ^ sw))) + (float)acc[0 + hh][reg] * s_comb;
          float zf = b2f(*(const unsigned short*)(zr + (((1 * 256 + ch) * 2) ^ sw))) + (float)acc[2 + hh][reg] * s_comb;
          float zg = b2f(*(const unsigned short*)(zr + (((2 * 256 + ch) * 2) ^ sw))) + (float)acc[4 + hh][reg] * s_comb;
          float zo = b2f(*(const unsigned short*)(zr + (((3 * 256 + ch) * 2) ^ sw))) + (float)acc[6 + hh][reg] * s_comb;
          float cv = fsig(zf) * cst[hh * 4 + reg] + fsig(zi) * ftanh(zg);
          cst[hh * 4 + reg] = cv;
          float hv = fsig(zo) * ftanh(cv);
          hbf[rr * 256 + (ch ^ ((rr & 7) << 3))] = (signed char)__float2int_rn(hv * 127.0f);
          if (n == 63) hm[(size_t)(b0 + rr) * 256 + ch] = hv;
        }
      }
    }
    __syncthreads();
  }
}

// ---------------------------------------------------------------------------
extern "C" void kernel_launch(void* const* d_in, const int* in_sizes, int n_in,
                              void* d_out, int out_size, void* d_ws, size_t ws_size,
                              hipStream_t stream){
  const float* x      = (const float*)d_in[0];
  const float* slots  = (const float*)d_in[2];
  const float* cum    = (const float*)d_in[3];
  const float* delta  = (const float*)d_in[4];
  const int*   filled = (const int*)d_in[5];
  const float* Wq  = (const float*)d_in[6];
  const float* Wk  = (const float*)d_in[7];
  const float* Wv  = (const float*)d_in[8];
  const float* bv  = (const float*)d_in[9];
  const float* wih = (const float*)d_in[10];
  const float* whh = (const float*)d_in[11];
  const float* bih = (const float*)d_in[12];
  const float* bhh = (const float*)d_in[13];

  float* out        = (float*)d_out;
  float* hm         = out;                 // (B,H)    524288
  float* slots_out  = out + 524288;        // (B,N,D)  33554432
  float* cum_out    = out + 34078720;      // (B,N,D)  33554432
  float* delta_out  = out + 67633152;      // (B,N)    131072
  float* filled_out = out + 67764224;      // (B,N)    131072

  char* ws = (char*)d_ws;
  int*            idx_ws  = (int*)ws;                                  // 8KB
  float*          v_ws    = (float*)(ws + 8192);                       // 2MB
  float*          bias    = (float*)(ws + 2105344);                    // 4KB
  float*          wlast   = (float*)(ws + 2109440);                    // 4KB
  unsigned short* wfB     = (unsigned short*)(ws + 2113536);           // 1MB
  signed char*    wfrag8  = (signed char*)(ws + 3162112);              // 256KB
  unsigned short* abf     = (unsigned short*)(ws + 3686400);           // 128MB
  unsigned short* z0      = (unsigned short*)(ws + 3686400 + 134217728); // 256MB

  k_prep<<<dim3(2048), dim3(256), 0, stream>>>(wih, whh, bih, bhh, wfB, wfrag8, bias, wlast);
  k_route<<<dim3(2048), dim3(256), 0, stream>>>(x, slots, delta, filled, Wq, Wk, Wv, bv,
                                                idx_ws, v_ws, delta_out, filled_out);
  k_scatter<<<dim3(32768), dim3(256), 0, stream>>>(x, slots, cum, idx_ws, v_ws,
                                                   slots_out, cum_out, abf);
  k_gemm<<<dim3(8192), dim3(256), 0, stream>>>(abf, delta_out,
                                               wfB, wlast, bias, z0);
  k_lstm<<<dim3(256), dim3(512), 36864, stream>>>(z0, wfrag8, hm);
}

// Round 13
// 659.056 us; speedup vs baseline: 1.5508x; 1.1173x over previous
//
#include <hip/hip_runtime.h>
#include <hip/hip_bf16.h>
#include <cstdint>
#include <cstddef>

// B=2048, D=256, H=256, N=64, F=513, 4H=1024

typedef short s16x8 __attribute__((ext_vector_type(8)));
typedef float f32x4 __attribute__((ext_vector_type(4)));
typedef int   i32x4 __attribute__((ext_vector_type(4)));

static __device__ __forceinline__ unsigned short f2b(float f){
  union{float f; unsigned int u;} v; v.f = f;
  unsigned int r = v.u + 0x7fffu + ((v.u >> 16) & 1u);   // RNE
  return (unsigned short)(r >> 16);
}
static __device__ __forceinline__ float b2f(unsigned short h){
  union{unsigned int u; float f;} v; v.u = ((unsigned int)h) << 16; return v.f;
}
static __device__ __forceinline__ unsigned int pack2(float a, float b){
  return (unsigned int)f2b(a) | ((unsigned int)f2b(b) << 16);
}
static __device__ __forceinline__ float fsig(float x){ return 1.0f / (1.0f + __expf(-x)); }
static __device__ __forceinline__ float ftanh(float x){ return 2.0f / (1.0f + __expf(-2.0f * x)) - 1.0f; }
static __device__ __forceinline__ float wred(float p){
  p += __shfl_down(p, 32); p += __shfl_down(p, 16); p += __shfl_down(p, 8);
  p += __shfl_down(p, 4);  p += __shfl_down(p, 2);  p += __shfl_down(p, 1);
  return p;
}
// async global->LDS, 16 B per lane; lds base wave-uniform, global src per-lane
static __device__ __forceinline__ void gload16(const void* g, void* lds){
  __builtin_amdgcn_global_load_lds(
      (const __attribute__((address_space(1))) unsigned int*)g,
      (__attribute__((address_space(3))) unsigned int*)lds, 16, 0, 0);
}

#define WSCALE (0.30f / 127.0f)      // W_hh i8 scale

// ---------------------------------------------------------------------------
// K0: weight prep. wfB: W_ih bf16 B-fragments, kt-major (frag = kt*64 + ct).
// wfrag8: W_hh int8 B-fragments for k_lstm. bias = b_ih+b_hh; wlast = W_ih[:,512].
// ---------------------------------------------------------------------------
__global__ __launch_bounds__(256) void k_prep(
    const float* __restrict__ wih, const float* __restrict__ whh,
    const float* __restrict__ bih, const float* __restrict__ bhh,
    unsigned short* __restrict__ wfB, signed char* __restrict__ wfrag8,
    float* __restrict__ bias, float* __restrict__ wlast){
  int id = blockIdx.x * 256 + threadIdx.x;          // grid covers 524288
  { // wfB: 1024 frags * 512 entries, kt-major
    int frag = id >> 9;
    int l = (id >> 3) & 63;
    int j = id & 7;
    int kt = frag >> 6, ct = frag & 63;
    int col = ct * 16 + (l & 15);
    int k   = kt * 32 + (l >> 4) * 8 + j;
    wfB[id] = f2b(wih[col * 513 + k]);
  }
  if (id < 262144){ // wfrag8: 512 frags * 512 entries, int8
    int frag = id >> 9;
    int lane = (id >> 3) & 63;
    int j    = id & 7;
    int w  = frag >> 6;
    int kt = (frag >> 3) & 7;
    int nt = frag & 7;
    int g  = nt >> 1, hh = nt & 1;
    int colg = g * 256 + w * 32 + hh * 16 + (lane & 15);
    int k    = kt * 32 + (lane >> 4) * 8 + j;
    int q = __float2int_rn(whh[colg * 256 + k] * (1.0f / WSCALE));
    q = q > 127 ? 127 : (q < -127 ? -127 : q);
    wfrag8[frag * 512 + lane * 8 + j] = (signed char)q;
  }
  if (id < 1024){
    bias[id]  = bih[id] + bhh[id];
    wlast[id] = wih[id * 513 + 512];
  }
}

// ---------------------------------------------------------------------------
// K1: routing (fast path = first empty slot via ballot; sims fallback kept).
// ---------------------------------------------------------------------------
__global__ __launch_bounds__(256) void k_route(
    const float* __restrict__ x, const float* __restrict__ slots,
    const float* __restrict__ delta, const int* __restrict__ filled,
    const float* __restrict__ Wq, const float* __restrict__ Wk,
    const float* __restrict__ Wv, const float* __restrict__ bv,
    int* __restrict__ idx_ws, float* __restrict__ v_ws,
    float* __restrict__ delta_out, float* __restrict__ filled_out){
  int b = blockIdx.x, tid = threadIdx.x, l = tid & 63, w = tid >> 6;
  __shared__ float xs[256], qs[256], qks[256], sims[64];
  __shared__ int sidx;
  xs[tid] = x[b * 256 + tid];
  if (tid < 64){
    unsigned long long em = __ballot(filled[b * 64 + tid] == 0);
    if (tid == 0) sidx = em ? (int)__builtin_ctzll(em) : -1;
  }
  __syncthreads();
  for (int t = 0; t < 64; ++t){
    int h = w * 64 + t;
    float pv = 0.f;
    #pragma unroll
    for (int j2 = 0; j2 < 4; ++j2)
      pv += Wv[h * 256 + l + 64 * j2] * xs[l + 64 * j2];
    pv = wred(pv);
    if (l == 0) v_ws[b * 256 + h] = pv + bv[h];
  }
  if (sidx < 0){           // rare fallback: content-based argmax
    for (int t = 0; t < 64; ++t){
      int h = w * 64 + t;
      float p = 0.f;
      #pragma unroll
      for (int j2 = 0; j2 < 4; ++j2)
        p += Wq[h * 256 + l + 64 * j2] * xs[l + 64 * j2];
      p = wred(p);
      if (l == 0) qs[h] = p;
    }
    __syncthreads();
    {
      int d = tid; float p = 0.f;
      for (int h = 0; h < 256; ++h) p += qs[h] * Wk[h * 256 + d];
      qks[d] = p;
    }
    __syncthreads();
    for (int t = 0; t < 16; ++t){
      int n = w * 16 + t;
      float p = 0.f;
      #pragma unroll
      for (int j2 = 0; j2 < 4; ++j2)
        p += slots[(size_t)(b * 64 + n) * 256 + l + 64 * j2] * qks[l + 64 * j2];
      p = wred(p);
      if (l == 0) sims[n] = p;
    }
    __syncthreads();
    if (tid == 0){
      int ic = 0; float best = sims[0];
      for (int n = 1; n < 64; ++n) if (sims[n] > best){ best = sims[n]; ic = n; }
      sidx = ic;
    }
  }
  __syncthreads();
  int id = sidx;
  if (tid == 0) idx_ws[b] = id;
  if (tid < 64){
    int n = tid; bool sel = (n == id);
    delta_out[b * 64 + n]  = sel ? 0.0f : (delta[b * 64 + n] + 1.0f);
    filled_out[b * 64 + n] = (sel || filled[b * 64 + n] != 0) ? 1.0f : 0.0f;
  }
}

// ---------------------------------------------------------------------------
// K2 v2: scatter/copy + bf16 A production (unchanged).
// ---------------------------------------------------------------------------
__global__ __launch_bounds__(256) void k_scatter(
    const float* __restrict__ x, const float* __restrict__ slots,
    const float* __restrict__ cum, const int* __restrict__ idx_ws,
    const float* __restrict__ v_ws,
    float* __restrict__ slots_out, float* __restrict__ cum_out,
    unsigned short* __restrict__ abf){
  int rg = threadIdx.x >> 6, l = threadIdx.x & 63;
  int row = blockIdx.x * 4 + rg;
  int b = row >> 6, n = row & 63;
  bool sel = (n == idx_ws[b]);
  float4 f0, f1;
  if (l < 32){
    int k0 = l * 8;
    const float* src = sel ? (v_ws + (size_t)b * 256 + k0)
                           : (slots + (size_t)row * 256 + k0);
    f0 = ((const float4*)src)[0]; f1 = ((const float4*)src)[1];
    float4* d = (float4*)(slots_out + (size_t)row * 256 + k0);
    d[0] = f0; d[1] = f1;
  } else {
    int k0 = (l - 32) * 8;
    const float4* xp = (const float4*)(x + (size_t)b * 256 + k0);
    float4 x0 = xp[0], x1 = xp[1];
    if (sel){ f0 = x0; f1 = x1; }
    else {
      const float4* cp = (const float4*)(cum + (size_t)row * 256 + k0);
      f0 = cp[0]; f1 = cp[1];
      f0.x += x0.x; f0.y += x0.y; f0.z += x0.z; f0.w += x0.w;
      f1.x += x1.x; f1.y += x1.y; f1.z += x1.z; f1.w += x1.w;
    }
    float4* d = (float4*)(cum_out + (size_t)row * 256 + k0);
    d[0] = f0; d[1] = f1;
  }
  uint4 q;
  q.x = pack2(f0.x, f0.y); q.y = pack2(f0.z, f0.w);
  q.z = pack2(f1.x, f1.y); q.w = pack2(f1.z, f1.w);
  *(uint4*)(abf + (size_t)row * 512 + l * 8) = q;   // l*8 covers both halves
}

// ---------------------------------------------------------------------------
// K3 v12: pure bf16 GEMM with T4 counted-vmcnt depth-2 pipeline (unchanged).
// ---------------------------------------------------------------------------
__global__ __launch_bounds__(256) void k_gemm(
    const unsigned short* __restrict__ abf,
    const float* __restrict__ dlt,
    const unsigned short* __restrict__ wfB,
    const float* __restrict__ wlast, const float* __restrict__ bias,
    unsigned short* __restrict__ z0){
  __shared__ unsigned char L[49152];
  int tid = threadIdx.x, l = tid & 63, w = tid >> 6;
  int bid = blockIdx.x;
  int gw = (bid & 7) * 1024 + (bid >> 3);        // XCD-chunked bijection
  int n_idx = gw & 7, m_idx = gw >> 3;
  int m0 = m_idx * 128, n0 = n_idx * 128, bA = m0 >> 6;
  int wm = w & 1, wn = w >> 1, cl = l & 15, lhi = l >> 4;
  int arow = tid & 127, akq = tid >> 7;          // staging: thread -> (kq,row)

  auto stageA = [&](int kt, int abase){
    const unsigned short* s = abf + (size_t)(m0 + arow) * 512 + kt * 32 + akq * 8;
    gload16(s,      L + abase + w * 1024);          // kq 0/1
    gload16(s + 16, L + abase + 4096 + w * 1024);   // kq 2/3
  };
  auto stageB = [&](int kt, int bbase){
    const unsigned short* s = wfB + ((size_t)(kt * 64 + n_idx * 8 + w * 2)) * 512 + l * 8;
    gload16(s, L + bbase + w * 2048);
    gload16(s + 512, L + bbase + w * 2048 + 1024);
  };

  f32x4 acc[4][4];
  #pragma unroll
  for (int mi = 0; mi < 4; ++mi)
    #pragma unroll
    for (int ni = 0; ni < 4; ++ni){ f32x4 zr = {0.f,0.f,0.f,0.f}; acc[mi][ni] = zr; }

  // prologue: stage tiles 0 and 1 (8 outstanding DMA/wave, issue order matters)
  stageA(0, 0);      stageB(0, 24576);
  stageA(1, 8192);   stageB(1, 32768);

  #pragma unroll
  for (int kt = 0; kt < 16; ++kt){
    if (kt < 14){
      int nb = (kt + 2) % 3;
      stageA(kt + 2, nb * 8192);
      stageB(kt + 2, 24576 + nb * 8192);
    }
    // counted wait: tile kt's 4 DMAs (per wave) have landed; never drain to 0
    if (kt < 14)       asm volatile("s_waitcnt vmcnt(8)" ::: "memory");
    else if (kt == 14) asm volatile("s_waitcnt vmcnt(4)" ::: "memory");
    else               asm volatile("s_waitcnt vmcnt(0)" ::: "memory");
    __builtin_amdgcn_s_barrier();                // all waves' tile-kt landed
    __builtin_amdgcn_sched_barrier(0);
    int ab = (kt % 3) * 8192, bb = 24576 + (kt % 3) * 8192;
    s16x8 a[4], bf[4];
    #pragma unroll
    for (int mi = 0; mi < 4; ++mi)
      a[mi] = *(const s16x8*)(L + ab + lhi * 2048 + (wm * 64 + mi * 16 + cl) * 16);
    #pragma unroll
    for (int ni = 0; ni < 4; ++ni)
      bf[ni] = *(const s16x8*)(L + bb + (wn * 4 + ni) * 1024 + l * 16);
    #pragma unroll
    for (int ni = 0; ni < 4; ++ni)
      #pragma unroll
      for (int mi = 0; mi < 4; ++mi)
        acc[mi][ni] = __builtin_amdgcn_mfma_f32_16x16x32_bf16(a[mi], bf[ni], acc[mi][ni], 0, 0, 0);
    __builtin_amdgcn_sched_barrier(0);
    __builtin_amdgcn_s_barrier();                // reads done before buf reuse
  }

  // epilogue: acc -> L (z-stage, 128 rows x 256 B) -> coalesced z0 stores
  float dv[4][4];
  #pragma unroll
  for (int mi = 0; mi < 4; ++mi)
    #pragma unroll
    for (int reg = 0; reg < 4; ++reg)
      dv[mi][reg] = dlt[(bA + wm) * 64 + mi * 16 + lhi * 4 + reg];
  #pragma unroll
  for (int mi = 0; mi < 4; ++mi)
    #pragma unroll
    for (int reg = 0; reg < 4; ++reg){
      int row = wm * 64 + mi * 16 + lhi * 4 + reg;
      #pragma unroll
      for (int ni = 0; ni < 4; ++ni){
        int col = wn * 64 + ni * 16 + cl;
        int gc = n0 + col;
        float val = acc[mi][ni][reg] + dv[mi][reg] * wlast[gc] + bias[gc];
        *(unsigned short*)(L + row * 256 + ((col * 2) ^ ((row & 7) << 4))) = f2b(val);
      }
    }
  __syncthreads();
  #pragma unroll
  for (int rr = 0; rr < 8; ++rr){
    int row = w * 32 + rr * 4 + lhi;
    int bq = bA + (row >> 6), nq = row & 63;
    uint4 v = *(const uint4*)(L + row * 256 + ((cl * 16) ^ ((row & 7) << 4)));
    *(uint4*)(z0 + ((size_t)nq * 2048 + bq) * 1024 + n0 + cl * 8) = v;
  }
}

// ---------------------------------------------------------------------------
// K4 v7: recurrent LSTM, int8 register-resident W_hh, 256 blocks x 8 rows.
// Gate phase now ALL-LANE: lanes l<32 bounce acc through a 32KB zhh LDS
// tile (float4 {i,f,g,o} per (row,col), b128 conflict-free); then all 512
// threads each own 4 fixed (row,col) items (c-state cst[4], static index).
// LDS: zbuf 2x16KB @0; zhh 32KB @32768; hbf 4KB @65536.
// ---------------------------------------------------------------------------
__global__ __launch_bounds__(512) void k_lstm(
    const unsigned short* __restrict__ z0,
    const signed char* __restrict__ wfrag8,
    float* __restrict__ hm){
  extern __shared__ unsigned char smem[];
  unsigned char* zbuf = smem;                 // 2 x 16 KB
  unsigned char* zhh  = smem + 32768;         // 8 x 256 x float4 = 32 KB
  unsigned char* hbf  = smem + 65536;         // 16 x 256 int8 = 4 KB, swizzled
  int tid = threadIdx.x, l = tid & 63, w = tid >> 6;
  int cl = l & 15, lhi = l >> 4;
  int b0 = blockIdx.x * 8;

  for (int i = tid; i < 1024; i += 512) ((unsigned int*)hbf)[i] = 0u;

  // resident weights: 64 frags x 8 B (128 regs; AGPR-eligible on gfx950)
  long long wpin[64];
  #pragma unroll
  for (int f = 0; f < 64; ++f)
    wpin[f] = *(const long long*)(wfrag8 + ((size_t)w * 64 + f) * 512 + l * 8);

  // prologue: z slice n=0 -> buf0 (16B-granule row-XOR swizzle)
  {
    const uint4* src = (const uint4*)(z0 + (size_t)b0 * 1024);
    int rr = tid >> 6, off = (tid & 63) * 32;
    unsigned char* base = zbuf + rr * 2048;
    *(uint4*)(base + ((off)      ^ ((rr & 7) << 4))) = src[tid * 2];
    *(uint4*)(base + ((off + 16) ^ ((rr & 7) << 4))) = src[tid * 2 + 1];
  }
  float cst[4];
  #pragma unroll
  for (int i = 0; i < 4; ++i) cst[i] = 0.f;
  const float s_comb = WSCALE / 127.0f;       // acc_i32 -> z_hh f32
  __syncthreads();

  for (int n = 0; n < 64; ++n){
    // T14: issue z prefetch for step n+1 (commits after MFMA)
    uint4 zp0, zp1;
    if (n < 63){
      const uint4* src = (const uint4*)(z0 + ((size_t)(n + 1) * 2048 + b0) * 1024);
      zp0 = src[tid * 2]; zp1 = src[tid * 2 + 1];
    }
    // MFMA: z_hh = h8 @ W8^T, weights from registers (rows 8-15 zero)
    i32x4 acc[8];
    #pragma unroll
    for (int nt = 0; nt < 8; ++nt){ i32x4 zr = {0, 0, 0, 0}; acc[nt] = zr; }
    #pragma unroll
    for (int kt = 0; kt < 8; ++kt){
      int byteo = cl * 256 + ((kt * 32 + lhi * 8) ^ ((cl & 7) << 3));
      long long a = *(const long long*)(hbf + byteo);
      #pragma unroll
      for (int nt = 0; nt < 8; ++nt)
        acc[nt] = __builtin_amdgcn_mfma_i32_16x16x32_i8(a, wpin[kt * 8 + nt], acc[nt], 0, 0, 0);
    }
    // commit z prefetch to the other buffer
    if (n < 63){
      int rr = tid >> 6, off = (tid & 63) * 32;
      unsigned char* base = zbuf + ((n + 1) & 1) * 16384 + rr * 2048;
      *(uint4*)(base + ((off)      ^ ((rr & 7) << 4))) = zp0;
      *(uint4*)(base + ((off + 16) ^ ((rr & 7) << 4))) = zp1;
    }
    // bounce acc -> zhh (lanes l<32 hold the 8 real rows)
    if (l < 32){
      #pragma unroll
      for (int hh = 0; hh < 2; ++hh){
        int ch = w * 32 + hh * 16 + cl;           // h column 0..255
        #pragma unroll
        for (int reg = 0; reg < 4; ++reg){
          int rr = lhi * 4 + reg;                 // row 0..7
          float4 v;
          v.x = (float)acc[0 + hh][reg];
          v.y = (float)acc[2 + hh][reg];
          v.z = (float)acc[4 + hh][reg];
          v.w = (float)acc[6 + hh][reg];
          *(float4*)(zhh + (rr * 256 + ch) * 16) = v;
        }
      }
    }
    __syncthreads();
    // gate phase: ALL 512 threads, 4 (row,col) items each
    const unsigned char* zc = zbuf + (n & 1) * 16384;
    #pragma unroll
    for (int i = 0; i < 4; ++i){
      int id = tid + i * 512;                     // 0..2047
      int rr = id >> 8, ch = id & 255;
      float4 a4 = *(const float4*)(zhh + id * 16);
      const unsigned char* zr = zc + rr * 2048;
      int sw = (rr & 7) << 4;
      float zi = fmaf(a4.x, s_comb, b2f(*(const unsigned short*)(zr + (((0 * 256 + ch) * 2) ^ sw))));
      float zf = fmaf(a4.y, s_comb, b2f(*(const unsigned short*)(zr + (((1 * 256 + ch) * 2) ^ sw))));
      float zg = fmaf(a4.z, s_comb, b2f(*(const unsigned short*)(zr + (((2 * 256 + ch) * 2) ^ sw))));
      float zo = fmaf(a4.w, s_comb, b2f(*(const unsigned short*)(zr + (((3 * 256 + ch) * 2) ^ sw))));
      float cv = fsig(zf) * cst[i] + fsig(zi) * ftanh(zg);
      cst[i] = cv;
      float hv = fsig(zo) * ftanh(cv);
      hbf[rr * 256 + (ch ^ ((rr & 7) << 3))] = (signed char)__float2int_rn(hv * 127.0f);
      if (n == 63) hm[(size_t)(b0 + rr) * 256 + ch] = hv;
    }
    __syncthreads();
  }
}

// ---------------------------------------------------------------------------
extern "C" void kernel_launch(void* const* d_in, const int* in_sizes, int n_in,
                              void* d_out, int out_size, void* d_ws, size_t ws_size,
                              hipStream_t stream){
  const float* x      = (const float*)d_in[0];
  const float* slots  = (const float*)d_in[2];
  const float* cum    = (const float*)d_in[3];
  const float* delta  = (const float*)d_in[4];
  const int*   filled = (const int*)d_in[5];
  const float* Wq  = (const float*)d_in[6];
  const float* Wk  = (const float*)d_in[7];
  const float* Wv  = (const float*)d_in[8];
  const float* bv  = (const float*)d_in[9];
  const float* wih = (const float*)d_in[10];
  const float* whh = (const float*)d_in[11];
  const float* bih = (const float*)d_in[12];
  const float* bhh = (const float*)d_in[13];

  float* out        = (float*)d_out;
  float* hm         = out;                 // (B,H)    524288
  float* slots_out  = out + 524288;        // (B,N,D)  33554432
  float* cum_out    = out + 34078720;      // (B,N,D)  33554432
  float* delta_out  = out + 67633152;      // (B,N)    131072
  float* filled_out = out + 67764224;      // (B,N)    131072

  char* ws = (char*)d_ws;
  int*            idx_ws  = (int*)ws;                                  // 8KB
  float*          v_ws    = (float*)(ws + 8192);                       // 2MB
  float*          bias    = (float*)(ws + 2105344);                    // 4KB
  float*          wlast   = (float*)(ws + 2109440);                    // 4KB
  unsigned short* wfB     = (unsigned short*)(ws + 2113536);           // 1MB
  signed char*    wfrag8  = (signed char*)(ws + 3162112);              // 256KB
  unsigned short* abf     = (unsigned short*)(ws + 3686400);           // 128MB
  unsigned short* z0      = (unsigned short*)(ws + 3686400 + 134217728); // 256MB

  k_prep<<<dim3(2048), dim3(256), 0, stream>>>(wih, whh, bih, bhh, wfB, wfrag8, bias, wlast);
  k_route<<<dim3(2048), dim3(256), 0, stream>>>(x, slots, delta, filled, Wq, Wk, Wv, bv,
                                                idx_ws, v_ws, delta_out, filled_out);
  k_scatter<<<dim3(32768), dim3(256), 0, stream>>>(x, slots, cum, idx_ws, v_ws,
                                                   slots_out, cum_out, abf);
  k_gemm<<<dim3(8192), dim3(256), 0, stream>>>(abf, delta_out,
                                               wfB, wlast, bias, z0);
  k_lstm<<<dim3(256), dim3(512), 69632, stream>>>(z0, wfrag8, hm);
}

// Round 14
// 598.036 us; speedup vs baseline: 1.7091x; 1.1020x over previous
//
#include <hip/hip_runtime.h>
#include <hip/hip_bf16.h>
#include <cstdint>
#include <cstddef>

// B=2048, D=256, H=256, N=64, F=513, 4H=1024

typedef short s16x8 __attribute__((ext_vector_type(8)));
typedef float f32x4 __attribute__((ext_vector_type(4)));
typedef int   i32x4 __attribute__((ext_vector_type(4)));

static __device__ __forceinline__ unsigned short f2b(float f){
  union{float f; unsigned int u;} v; v.f = f;
  unsigned int r = v.u + 0x7fffu + ((v.u >> 16) & 1u);   // RNE
  return (unsigned short)(r >> 16);
}
static __device__ __forceinline__ float b2f(unsigned short h){
  union{unsigned int u; float f;} v; v.u = ((unsigned int)h) << 16; return v.f;
}
static __device__ __forceinline__ unsigned int pack2(float a, float b){
  return (unsigned int)f2b(a) | ((unsigned int)f2b(b) << 16);
}
static __device__ __forceinline__ float fsig(float x){ return 1.0f / (1.0f + __expf(-x)); }
static __device__ __forceinline__ float ftanh(float x){ return 2.0f / (1.0f + __expf(-2.0f * x)) - 1.0f; }
static __device__ __forceinline__ float wred(float p){
  p += __shfl_down(p, 32); p += __shfl_down(p, 16); p += __shfl_down(p, 8);
  p += __shfl_down(p, 4);  p += __shfl_down(p, 2);  p += __shfl_down(p, 1);
  return p;
}
// async global->LDS, 16 B per lane; lds base wave-uniform, global src per-lane
static __device__ __forceinline__ void gload16(const void* g, void* lds){
  __builtin_amdgcn_global_load_lds(
      (const __attribute__((address_space(1))) unsigned int*)g,
      (__attribute__((address_space(3))) unsigned int*)lds, 16, 0, 0);
}

#define WSCALE (0.30f / 127.0f)      // W_hh i8 scale

// ---------------------------------------------------------------------------
// K0: weight prep. wfB: W_ih bf16 B-fragments, kt-major (frag = kt*64 + ct).
// wfrag8: W_hh int8 B-fragments for k_lstm. bias = b_ih+b_hh; wlast = W_ih[:,512].
// ---------------------------------------------------------------------------
__global__ __launch_bounds__(256) void k_prep(
    const float* __restrict__ wih, const float* __restrict__ whh,
    const float* __restrict__ bih, const float* __restrict__ bhh,
    unsigned short* __restrict__ wfB, signed char* __restrict__ wfrag8,
    float* __restrict__ bias, float* __restrict__ wlast){
  int id = blockIdx.x * 256 + threadIdx.x;          // grid covers 524288
  { // wfB: 1024 frags * 512 entries, kt-major
    int frag = id >> 9;
    int l = (id >> 3) & 63;
    int j = id & 7;
    int kt = frag >> 6, ct = frag & 63;
    int col = ct * 16 + (l & 15);
    int k   = kt * 32 + (l >> 4) * 8 + j;
    wfB[id] = f2b(wih[col * 513 + k]);
  }
  if (id < 262144){ // wfrag8: 512 frags * 512 entries, int8
    int frag = id >> 9;
    int lane = (id >> 3) & 63;
    int j    = id & 7;
    int w  = frag >> 6;
    int kt = (frag >> 3) & 7;
    int nt = frag & 7;
    int g  = nt >> 1, hh = nt & 1;
    int colg = g * 256 + w * 32 + hh * 16 + (lane & 15);
    int k    = kt * 32 + (lane >> 4) * 8 + j;
    int q = __float2int_rn(whh[colg * 256 + k] * (1.0f / WSCALE));
    q = q > 127 ? 127 : (q < -127 ? -127 : q);
    wfrag8[frag * 512 + lane * 8 + j] = (signed char)q;
  }
  if (id < 1024){
    bias[id]  = bih[id] + bhh[id];
    wlast[id] = wih[id * 513 + 512];
  }
}

// ---------------------------------------------------------------------------
// K1: routing (fast path = first empty slot via ballot; sims fallback kept).
// ---------------------------------------------------------------------------
__global__ __launch_bounds__(256) void k_route(
    const float* __restrict__ x, const float* __restrict__ slots,
    const float* __restrict__ delta, const int* __restrict__ filled,
    const float* __restrict__ Wq, const float* __restrict__ Wk,
    const float* __restrict__ Wv, const float* __restrict__ bv,
    int* __restrict__ idx_ws, float* __restrict__ v_ws,
    float* __restrict__ delta_out, float* __restrict__ filled_out){
  int b = blockIdx.x, tid = threadIdx.x, l = tid & 63, w = tid >> 6;
  __shared__ float xs[256], qs[256], qks[256], sims[64];
  __shared__ int sidx;
  xs[tid] = x[b * 256 + tid];
  if (tid < 64){
    unsigned long long em = __ballot(filled[b * 64 + tid] == 0);
    if (tid == 0) sidx = em ? (int)__builtin_ctzll(em) : -1;
  }
  __syncthreads();
  for (int t = 0; t < 64; ++t){
    int h = w * 64 + t;
    float pv = 0.f;
    #pragma unroll
    for (int j2 = 0; j2 < 4; ++j2)
      pv += Wv[h * 256 + l + 64 * j2] * xs[l + 64 * j2];
    pv = wred(pv);
    if (l == 0) v_ws[b * 256 + h] = pv + bv[h];
  }
  if (sidx < 0){           // rare fallback: content-based argmax
    for (int t = 0; t < 64; ++t){
      int h = w * 64 + t;
      float p = 0.f;
      #pragma unroll
      for (int j2 = 0; j2 < 4; ++j2)
        p += Wq[h * 256 + l + 64 * j2] * xs[l + 64 * j2];
      p = wred(p);
      if (l == 0) qs[h] = p;
    }
    __syncthreads();
    {
      int d = tid; float p = 0.f;
      for (int h = 0; h < 256; ++h) p += qs[h] * Wk[h * 256 + d];
      qks[d] = p;
    }
    __syncthreads();
    for (int t = 0; t < 16; ++t){
      int n = w * 16 + t;
      float p = 0.f;
      #pragma unroll
      for (int j2 = 0; j2 < 4; ++j2)
        p += slots[(size_t)(b * 64 + n) * 256 + l + 64 * j2] * qks[l + 64 * j2];
      p = wred(p);
      if (l == 0) sims[n] = p;
    }
    __syncthreads();
    if (tid == 0){
      int ic = 0; float best = sims[0];
      for (int n = 1; n < 64; ++n) if (sims[n] > best){ best = sims[n]; ic = n; }
      sidx = ic;
    }
  }
  __syncthreads();
  int id = sidx;
  if (tid == 0) idx_ws[b] = id;
  if (tid < 64){
    int n = tid; bool sel = (n == id);
    delta_out[b * 64 + n]  = sel ? 0.0f : (delta[b * 64 + n] + 1.0f);
    filled_out[b * 64 + n] = (sel || filled[b * 64 + n] != 0) ? 1.0f : 0.0f;
  }
}

// ---------------------------------------------------------------------------
// K2 v2: scatter/copy + bf16 A production (unchanged).
// ---------------------------------------------------------------------------
__global__ __launch_bounds__(256) void k_scatter(
    const float* __restrict__ x, const float* __restrict__ slots,
    const float* __restrict__ cum, const int* __restrict__ idx_ws,
    const float* __restrict__ v_ws,
    float* __restrict__ slots_out, float* __restrict__ cum_out,
    unsigned short* __restrict__ abf){
  int rg = threadIdx.x >> 6, l = threadIdx.x & 63;
  int row = blockIdx.x * 4 + rg;
  int b = row >> 6, n = row & 63;
  bool sel = (n == idx_ws[b]);
  float4 f0, f1;
  if (l < 32){
    int k0 = l * 8;
    const float* src = sel ? (v_ws + (size_t)b * 256 + k0)
                           : (slots + (size_t)row * 256 + k0);
    f0 = ((const float4*)src)[0]; f1 = ((const float4*)src)[1];
    float4* d = (float4*)(slots_out + (size_t)row * 256 + k0);
    d[0] = f0; d[1] = f1;
  } else {
    int k0 = (l - 32) * 8;
    const float4* xp = (const float4*)(x + (size_t)b * 256 + k0);
    float4 x0 = xp[0], x1 = xp[1];
    if (sel){ f0 = x0; f1 = x1; }
    else {
      const float4* cp = (const float4*)(cum + (size_t)row * 256 + k0);
      f0 = cp[0]; f1 = cp[1];
      f0.x += x0.x; f0.y += x0.y; f0.z += x0.z; f0.w += x0.w;
      f1.x += x1.x; f1.y += x1.y; f1.z += x1.z; f1.w += x1.w;
    }
    float4* d = (float4*)(cum_out + (size_t)row * 256 + k0);
    d[0] = f0; d[1] = f1;
  }
  uint4 q;
  q.x = pack2(f0.x, f0.y); q.y = pack2(f0.z, f0.w);
  q.z = pack2(f1.x, f1.y); q.w = pack2(f1.z, f1.w);
  *(uint4*)(abf + (size_t)row * 512 + l * 8) = q;   // l*8 covers both halves
}

// ---------------------------------------------------------------------------
// K3 v13: pure bf16 GEMM, 128x256 tile, 8 waves (512 thr), T4 counted-vmcnt
// depth-2 pipeline. Per wave per tile: 3 DMAs (A=1, B=2) -> steady vmcnt(6).
// 3 buffers per operand: A 3x8KB @0; B 3x16KB @24576 (72KB dynamic LDS ->
// 2 blocks/CU = 16 waves). Grid 4096 XCD-chunked: the 4 n-blocks of an
// m-panel share A via one XCD's L2. 2 barriers per kt (validated R12/R13).
// z0 step-major: z0[(n*2048 + b)*1024 + gc] (bf16); 512B-contiguous stores.
// ---------------------------------------------------------------------------
__global__ __launch_bounds__(512) void k_gemm(
    const unsigned short* __restrict__ abf,
    const float* __restrict__ dlt,
    const unsigned short* __restrict__ wfB,
    const float* __restrict__ wlast, const float* __restrict__ bias,
    unsigned short* __restrict__ z0){
  extern __shared__ unsigned char L[];           // 73728 B
  int tid = threadIdx.x, l = tid & 63, w = tid >> 6;
  int bid = blockIdx.x;
  int gw = (bid & 7) * 512 + (bid >> 3);         // XCD-chunked bijection (4096)
  int n_idx = gw & 3, m_idx = gw >> 2;           // 4 n-blocks x 1024 m-panels
  int m0 = m_idx * 128, n0 = n_idx * 256, bA = m0 >> 6;
  int wm = w & 1, wn = w >> 1;                   // 2 x 4 wave grid
  int cl = l & 15, lhi = l >> 4;

  auto stageA = [&](int kt, int abase){          // 8KB tile, 1 DMA/wave
    const unsigned short* s = abf + (size_t)(m0 + (w & 1) * 64 + l) * 512
                              + kt * 32 + (w >> 1) * 8;
    gload16(s, L + abase + (w >> 1) * 2048 + (w & 1) * 1024);
  };
  auto stageB = [&](int kt, int bbase){          // 16KB tile, 2 DMA/wave
    const unsigned short* s = wfB + ((size_t)(kt * 64 + n_idx * 16 + w * 2)) * 512 + l * 8;
    gload16(s,       L + bbase + (w * 2) * 1024);
    gload16(s + 512, L + bbase + (w * 2) * 1024 + 1024);
  };

  f32x4 acc[4][4];
  #pragma unroll
  for (int mi = 0; mi < 4; ++mi)
    #pragma unroll
    for (int ni = 0; ni < 4; ++ni){ f32x4 zr = {0.f,0.f,0.f,0.f}; acc[mi][ni] = zr; }

  // prologue: stage tiles 0 and 1 (6 outstanding DMA/wave)
  stageA(0, 0);      stageB(0, 24576);
  stageA(1, 8192);   stageB(1, 24576 + 16384);

  #pragma unroll
  for (int kt = 0; kt < 16; ++kt){
    if (kt < 14){
      int nb = (kt + 2) % 3;
      stageA(kt + 2, nb * 8192);
      stageB(kt + 2, 24576 + nb * 16384);
    }
    // counted wait: tile kt's 3 DMAs (per wave) have landed; never drain to 0
    if (kt < 14)       asm volatile("s_waitcnt vmcnt(6)" ::: "memory");
    else if (kt == 14) asm volatile("s_waitcnt vmcnt(3)" ::: "memory");
    else               asm volatile("s_waitcnt vmcnt(0)" ::: "memory");
    __builtin_amdgcn_s_barrier();                // all waves' tile-kt landed
    __builtin_amdgcn_sched_barrier(0);
    int ab = (kt % 3) * 8192, bb = 24576 + (kt % 3) * 16384;
    s16x8 a[4], bf[4];
    #pragma unroll
    for (int mi = 0; mi < 4; ++mi)
      a[mi] = *(const s16x8*)(L + ab + lhi * 2048 + (wm * 64 + mi * 16 + cl) * 16);
    #pragma unroll
    for (int ni = 0; ni < 4; ++ni)
      bf[ni] = *(const s16x8*)(L + bb + (wn * 4 + ni) * 1024 + l * 16);
    #pragma unroll
    for (int ni = 0; ni < 4; ++ni)
      #pragma unroll
      for (int mi = 0; mi < 4; ++mi)
        acc[mi][ni] = __builtin_amdgcn_mfma_f32_16x16x32_bf16(a[mi], bf[ni], acc[mi][ni], 0, 0, 0);
    __builtin_amdgcn_sched_barrier(0);
    __builtin_amdgcn_s_barrier();                // reads done before buf reuse
  }

  // epilogue: acc -> L (z-stage, 128 rows x 512 B) -> coalesced z0 stores
  float dv[4][4];
  #pragma unroll
  for (int mi = 0; mi < 4; ++mi)
    #pragma unroll
    for (int reg = 0; reg < 4; ++reg)
      dv[mi][reg] = dlt[(bA + wm) * 64 + mi * 16 + lhi * 4 + reg];
  #pragma unroll
  for (int mi = 0; mi < 4; ++mi)
    #pragma unroll
    for (int reg = 0; reg < 4; ++reg){
      int row = wm * 64 + mi * 16 + lhi * 4 + reg;
      #pragma unroll
      for (int ni = 0; ni < 4; ++ni){
        int col = wn * 64 + ni * 16 + cl;        // 0..255
        int gc = n0 + col;
        float val = acc[mi][ni][reg] + dv[mi][reg] * wlast[gc] + bias[gc];
        *(unsigned short*)(L + row * 512 + ((col * 2) ^ ((row & 7) << 4))) = f2b(val);
      }
    }
  __syncthreads();
  #pragma unroll
  for (int rr = 0; rr < 8; ++rr){
    int id = rr * 512 + tid;                     // 4096 16B chunks
    int row = id >> 5, cs = id & 31;
    int bq = bA + (row >> 6), nq = row & 63;
    uint4 v = *(const uint4*)(L + row * 512 + ((cs * 16) ^ ((row & 7) << 4)));
    *(uint4*)(z0 + ((size_t)nq * 2048 + bq) * 1024 + n0 + cs * 8) = v;
  }
}

// ---------------------------------------------------------------------------
// K4 v7: recurrent LSTM, int8 register-resident W_hh, 256 blocks x 8 rows.
// All-lane gate phase via zhh LDS bounce (unchanged from R13).
// ---------------------------------------------------------------------------
__global__ __launch_bounds__(512) void k_lstm(
    const unsigned short* __restrict__ z0,
    const signed char* __restrict__ wfrag8,
    float* __restrict__ hm){
  extern __shared__ unsigned char smem[];
  unsigned char* zbuf = smem;                 // 2 x 16 KB
  unsigned char* zhh  = smem + 32768;         // 8 x 256 x float4 = 32 KB
  unsigned char* hbf  = smem + 65536;         // 16 x 256 int8 = 4 KB, swizzled
  int tid = threadIdx.x, l = tid & 63, w = tid >> 6;
  int cl = l & 15, lhi = l >> 4;
  int b0 = blockIdx.x * 8;

  for (int i = tid; i < 1024; i += 512) ((unsigned int*)hbf)[i] = 0u;

  // resident weights: 64 frags x 8 B (128 regs)
  long long wpin[64];
  #pragma unroll
  for (int f = 0; f < 64; ++f)
    wpin[f] = *(const long long*)(wfrag8 + ((size_t)w * 64 + f) * 512 + l * 8);

  // prologue: z slice n=0 -> buf0 (16B-granule row-XOR swizzle)
  {
    const uint4* src = (const uint4*)(z0 + (size_t)b0 * 1024);
    int rr = tid >> 6, off = (tid & 63) * 32;
    unsigned char* base = zbuf + rr * 2048;
    *(uint4*)(base + ((off)      ^ ((rr & 7) << 4))) = src[tid * 2];
    *(uint4*)(base + ((off + 16) ^ ((rr & 7) << 4))) = src[tid * 2 + 1];
  }
  float cst[4];
  #pragma unroll
  for (int i = 0; i < 4; ++i) cst[i] = 0.f;
  const float s_comb = WSCALE / 127.0f;       // acc_i32 -> z_hh f32
  __syncthreads();

  for (int n = 0; n < 64; ++n){
    // T14: issue z prefetch for step n+1 (commits after MFMA)
    uint4 zp0, zp1;
    if (n < 63){
      const uint4* src = (const uint4*)(z0 + ((size_t)(n + 1) * 2048 + b0) * 1024);
      zp0 = src[tid * 2]; zp1 = src[tid * 2 + 1];
    }
    // MFMA: z_hh = h8 @ W8^T, weights from registers (rows 8-15 zero)
    i32x4 acc[8];
    #pragma unroll
    for (int nt = 0; nt < 8; ++nt){ i32x4 zr = {0, 0, 0, 0}; acc[nt] = zr; }
    #pragma unroll
    for (int kt = 0; kt < 8; ++kt){
      int byteo = cl * 256 + ((kt * 32 + lhi * 8) ^ ((cl & 7) << 3));
      long long a = *(const long long*)(hbf + byteo);
      #pragma unroll
      for (int nt = 0; nt < 8; ++nt)
        acc[nt] = __builtin_amdgcn_mfma_i32_16x16x32_i8(a, wpin[kt * 8 + nt], acc[nt], 0, 0, 0);
    }
    // commit z prefetch to the other buffer
    if (n < 63){
      int rr = tid >> 6, off = (tid & 63) * 32;
      unsigned char* base = zbuf + ((n + 1) & 1) * 16384 + rr * 2048;
      *(uint4*)(base + ((off)      ^ ((rr & 7) << 4))) = zp0;
      *(uint4*)(base + ((off + 16) ^ ((rr & 7) << 4))) = zp1;
    }
    // bounce acc -> zhh (lanes l<32 hold the 8 real rows)
    if (l < 32){
      #pragma unroll
      for (int hh = 0; hh < 2; ++hh){
        int ch = w * 32 + hh * 16 + cl;           // h column 0..255
        #pragma unroll
        for (int reg = 0; reg < 4; ++reg){
          int rr = lhi * 4 + reg;                 // row 0..7
          float4 v;
          v.x = (float)acc[0 + hh][reg];
          v.y = (float)acc[2 + hh][reg];
          v.z = (float)acc[4 + hh][reg];
          v.w = (float)acc[6 + hh][reg];
          *(float4*)(zhh + (rr * 256 + ch) * 16) = v;
        }
      }
    }
    __syncthreads();
    // gate phase: ALL 512 threads, 4 (row,col) items each
    const unsigned char* zc = zbuf + (n & 1) * 16384;
    #pragma unroll
    for (int i = 0; i < 4; ++i){
      int id = tid + i * 512;                     // 0..2047
      int rr = id >> 8, ch = id & 255;
      float4 a4 = *(const float4*)(zhh + id * 16);
      const unsigned char* zr = zc + rr * 2048;
      int sw = (rr & 7) << 4;
      float zi = fmaf(a4.x, s_comb, b2f(*(const unsigned short*)(zr + (((0 * 256 + ch) * 2) ^ sw))));
      float zf = fmaf(a4.y, s_comb, b2f(*(const unsigned short*)(zr + (((1 * 256 + ch) * 2) ^ sw))));
      float zg = fmaf(a4.z, s_comb, b2f(*(const unsigned short*)(zr + (((2 * 256 + ch) * 2) ^ sw))));
      float zo = fmaf(a4.w, s_comb, b2f(*(const unsigned short*)(zr + (((3 * 256 + ch) * 2) ^ sw))));
      float cv = fsig(zf) * cst[i] + fsig(zi) * ftanh(zg);
      cst[i] = cv;
      float hv = fsig(zo) * ftanh(cv);
      hbf[rr * 256 + (ch ^ ((rr & 7) << 3))] = (signed char)__float2int_rn(hv * 127.0f);
      if (n == 63) hm[(size_t)(b0 + rr) * 256 + ch] = hv;
    }
    __syncthreads();
  }
}

// ---------------------------------------------------------------------------
extern "C" void kernel_launch(void* const* d_in, const int* in_sizes, int n_in,
                              void* d_out, int out_size, void* d_ws, size_t ws_size,
                              hipStream_t stream){
  const float* x      = (const float*)d_in[0];
  const float* slots  = (const float*)d_in[2];
  const float* cum    = (const float*)d_in[3];
  const float* delta  = (const float*)d_in[4];
  const int*   filled = (const int*)d_in[5];
  const float* Wq  = (const float*)d_in[6];
  const float* Wk  = (const float*)d_in[7];
  const float* Wv  = (const float*)d_in[8];
  const float* bv  = (const float*)d_in[9];
  const float* wih = (const float*)d_in[10];
  const float* whh = (const float*)d_in[11];
  const float* bih = (const float*)d_in[12];
  const float* bhh = (const float*)d_in[13];

  float* out        = (float*)d_out;
  float* hm         = out;                 // (B,H)    524288
  float* slots_out  = out + 524288;        // (B,N,D)  33554432
  float* cum_out    = out + 34078720;      // (B,N,D)  33554432
  float* delta_out  = out + 67633152;      // (B,N)    131072
  float* filled_out = out + 67764224;      // (B,N)    131072

  char* ws = (char*)d_ws;
  int*            idx_ws  = (int*)ws;                                  // 8KB
  float*          v_ws    = (float*)(ws + 8192);                       // 2MB
  float*          bias    = (float*)(ws + 2105344);                    // 4KB
  float*          wlast   = (float*)(ws + 2109440);                    // 4KB
  unsigned short* wfB     = (unsigned short*)(ws + 2113536);           // 1MB
  signed char*    wfrag8  = (signed char*)(ws + 3162112);              // 256KB
  unsigned short* abf     = (unsigned short*)(ws + 3686400);           // 128MB
  unsigned short* z0      = (unsigned short*)(ws + 3686400 + 134217728); // 256MB

  k_prep<<<dim3(2048), dim3(256), 0, stream>>>(wih, whh, bih, bhh, wfB, wfrag8, bias, wlast);
  k_route<<<dim3(2048), dim3(256), 0, stream>>>(x, slots, delta, filled, Wq, Wk, Wv, bv,
                                                idx_ws, v_ws, delta_out, filled_out);
  k_scatter<<<dim3(32768), dim3(256), 0, stream>>>(x, slots, cum, idx_ws, v_ws,
                                                   slots_out, cum_out, abf);
  k_gemm<<<dim3(4096), dim3(512), 73728, stream>>>(abf, delta_out,
                                                   wfB, wlast, bias, z0);
  k_lstm<<<dim3(256), dim3(512), 69632, stream>>>(z0, wfrag8, hm);
}